// Round 5
// baseline (3998.215 us; speedup 1.0000x reference)
//
#include <hip/hip_runtime.h>

#define EPSV 1e-5f

__device__ __forceinline__ float fast_rcp(float x) { return __builtin_amdgcn_rcpf(x); }
__device__ __forceinline__ float sigm(float x) { return fast_rcp(1.0f + __expf(-x)); }
__device__ __forceinline__ float tanhfast(float x) {
    float e = __expf(2.0f * x);
    return 1.0f - 2.0f * fast_rcp(e + 1.0f);
}
__device__ __forceinline__ float dot4(const float4 w, const float4 v, float a) {
    a = fmaf(w.x, v.x, a);
    a = fmaf(w.y, v.y, a);
    a = fmaf(w.z, v.z, a);
    a = fmaf(w.w, v.w, a);
    return a;
}

// ------- pack: w2 -> w2t2[(i*32+o)*8+k]; w3 -> w3p4/w3p1[(i*16+o)]; zero LSTM flags -------
__global__ void pack_kernel(const float* __restrict__ w2, const float* __restrict__ w3,
                            float* __restrict__ w2t2, float4* __restrict__ w3p4,
                            float* __restrict__ w3p1, int* __restrict__ flags) {
    int j = blockIdx.x * 256 + threadIdx.x;
    if (j < 16384) {
        int i = j >> 8;
        int o = (j >> 3) & 31;
        int k = j & 7;
        w2t2[j] = (k < 7) ? w2[o * 448 + i * 7 + k] : 0.0f;
    } else if (j < 16896) {
        int e = j - 16384;            // e = i*16+o
        int i = e >> 4, o = e & 15;
        int base = o * 160 + i * 5;
        w3p4[e] = make_float4(w3[base], w3[base + 1], w3[base + 2], w3[base + 3]);
        w3p1[e] = w3[base + 4];
    } else if (j < 16912) {
        flags[j - 16896] = 0;         // d_ws is poisoned 0xAA every launch -> must re-zero
    }
}

// ---------------- CNN: one block per window (b,t) ---------------- (unchanged from R4)
__global__ __launch_bounds__(256) void cnn_kernel(
    const float* __restrict__ x,
    const float* __restrict__ w1, const float* __restrict__ b1,
    const float* __restrict__ g1, const float* __restrict__ be1,
    const float* __restrict__ m1, const float* __restrict__ v1,
    const float* __restrict__ b2,
    const float* __restrict__ g2, const float* __restrict__ be2,
    const float* __restrict__ m2, const float* __restrict__ v2,
    const float* __restrict__ b3,
    const float* __restrict__ g3, const float* __restrict__ be3,
    const float* __restrict__ m3, const float* __restrict__ v3,
    const float* __restrict__ w2t2,
    const float4* __restrict__ w3p4, const float* __restrict__ w3p1,
    float* __restrict__ feats)
{
    __shared__ float winh[64];
    __shared__ float w1t[9 * 64];
    __shared__ __align__(16) float a1[64 * 84 + 32];
    __shared__ __align__(16) float a2[32 * 56 + 16];
    __shared__ float s1[64], t1[64], s2[32], t2[32], s3[16], t3[16];
    __shared__ float psum[16 * 16];

    const int tid = threadIdx.x;
    const int w = blockIdx.x;
    const int b = w >> 11;
    const int t = w & 2047;

    for (int idx = tid; idx < 576; idx += 256) {
        int o = idx / 9, k = idx % 9;
        w1t[k * 64 + o] = w1[idx];
    }
    if (tid < 64) {
        float s = g1[tid] * rsqrtf(v1[tid] + EPSV);
        s1[tid] = s;
        t1[tid] = (b1[tid] - m1[tid]) * s + be1[tid];
    } else if (tid < 96) {
        int o = tid - 64;
        float s = g2[o] * rsqrtf(v2[o] + EPSV);
        s2[o] = s;
        t2[o] = (b2[o] - m2[o]) * s + be2[o];
    } else if (tid < 112) {
        int o = tid - 96;
        float s = g3[o] * rsqrtf(v3[o] + EPSV);
        s3[o] = s;
        t3[o] = (b3[o] - m3[o]) * s + be3[o];
    }
    if (tid < 64) {
        winh[tid] = 0.0f;
        float* r = &a1[tid * 84];
        r[0] = 0.f; r[1] = 0.f; r[2] = 0.f;
        r[77] = 0.f; r[78] = 0.f; r[79] = 0.f;
    }
    if (tid < 32) {
        float* r = &a2[tid * 56];
        r[0] = 0.f; r[1] = 0.f;
        r[52] = 0.f; r[53] = 0.f; r[54] = 0.f; r[55] = 0.f;
    }
    __syncthreads();
    if (tid < 50) {
        int gi = t + tid - 49;
        winh[4 + tid] = (gi >= 0) ? x[b * 2048 + gi] : 0.0f;
    }
    __syncthreads();

    {   // conv1
        int o = tid >> 2, pg = tid & 3;
        int p0 = pg * 13;
        float wv[9];
        #pragma unroll
        for (int k = 0; k < 9; ++k) wv[k] = w1t[k * 64 + o];
        float sc = s1[o], tc = t1[o];
        #pragma unroll
        for (int q = 0; q < 13; ++q) {
            int p = p0 + q;
            if (p < 50) {
                float acc = 0.0f;
                #pragma unroll
                for (int k = 0; k < 9; ++k) acc = fmaf(wv[k], winh[p + k], acc);
                int pi = p + 3;
                int slot = pi + ((pi >> 3) << 2);
                a1[o * 84 + slot] = fmaxf(acc * sc + tc, 0.0f);
            }
        }
    }
    __syncthreads();

    {   // conv2
        int o = tid >> 3, pg = tid & 7;
        float acc[8];
        #pragma unroll
        for (int q = 0; q < 8; ++q) acc[q] = 0.0f;
        for (int i = 0; i < 64; ++i) {
            const float* rowp = &a1[i * 84 + 12 * pg];
            float4 A0 = *(const float4*)&rowp[0];
            float4 A1 = *(const float4*)&rowp[4];
            float4 A2 = *(const float4*)&rowp[12];
            float2 A3 = *(const float2*)&rowp[16];
            const float4* wp = (const float4*)&w2t2[(i * 32 + o) * 8];
            float4 Wa = wp[0], Wb = wp[1];
            float av[14] = {A0.x, A0.y, A0.z, A0.w, A1.x, A1.y, A1.z, A1.w,
                            A2.x, A2.y, A2.z, A2.w, A3.x, A3.y};
            float wk[7] = {Wa.x, Wa.y, Wa.z, Wa.w, Wb.x, Wb.y, Wb.z};
            #pragma unroll
            for (int k = 0; k < 7; ++k) {
                #pragma unroll
                for (int q = 0; q < 8; ++q) acc[q] = fmaf(wk[k], av[q + k], acc[q]);
            }
        }
        float sc = s2[o], tc = t2[o];
        float r[8];
        #pragma unroll
        for (int q = 0; q < 8; ++q) r[q] = fmaxf(acc[q] * sc + tc, 0.0f);
        float* row = &a2[o * 56 + 8 * pg];
        if (pg < 6) {
            *(float2*)&row[2] = make_float2(r[0], r[1]);
            *(float4*)&row[4] = make_float4(r[2], r[3], r[4], r[5]);
            *(float2*)&row[8] = make_float2(r[6], r[7]);
        } else if (pg == 6) {
            *(float2*)&row[2] = make_float2(r[0], r[1]);
        }
    }
    __syncthreads();

    {   // conv3 + mean partials
        int o = tid & 15, pg = tid >> 4;
        float acc[4];
        #pragma unroll
        for (int q = 0; q < 4; ++q) acc[q] = 0.0f;
        for (int i = 0; i < 32; ++i) {
            float4 wa = w3p4[i * 16 + o];
            float w4 = w3p1[i * 16 + o];
            const float4* ap = (const float4*)&a2[i * 56 + 4 * pg];
            float4 Aa = ap[0], Ab = ap[1];
            float av[8] = {Aa.x, Aa.y, Aa.z, Aa.w, Ab.x, Ab.y, Ab.z, Ab.w};
            #pragma unroll
            for (int q = 0; q < 4; ++q) {
                acc[q] = fmaf(wa.x, av[q], acc[q]);
                acc[q] = fmaf(wa.y, av[q + 1], acc[q]);
                acc[q] = fmaf(wa.z, av[q + 2], acc[q]);
                acc[q] = fmaf(wa.w, av[q + 3], acc[q]);
                acc[q] = fmaf(w4,   av[q + 4], acc[q]);
            }
        }
        float sc = s3[o], tc = t3[o];
        float ps = 0.0f;
        #pragma unroll
        for (int q = 0; q < 4; ++q) {
            int p = 4 * pg + q;
            if (p < 50) ps += fmaxf(acc[q] * sc + tc, 0.0f);
        }
        psum[pg * 16 + o] = ps;
    }
    __syncthreads();

    if (tid < 16) {
        float s = 0.0f;
        #pragma unroll
        for (int pg = 0; pg < 16; ++pg) s += psum[pg * 16 + tid];
        feats[w * 16 + tid] = s * (1.0f / 50.0f);
    }
}

// ---------------- LSTM: 32 blocks x 512 threads ----------------
// Blocks 0-15: layer0 (producer) for batch b. Blocks 16-31: layer1 (consumer).
// Producer publishes h1(s) to global via agent-scope atomic stores; __syncthreads()
// drains vmcnt on ALL waves (gfx950 barrier semantics), then tid0 release-stores flag=s+1.
// Consumer acquire-spins flag >= s+1, then reads h1(s) via agent-scope atomic loads
// (bypasses stale per-XCD caches). Consumer's h2 recurrence stays LDS-local.
// Gate math identical to round-4 (8 lanes per h-element, 3-level butterfly, redundant cst).
__global__ __launch_bounds__(512, 2) void lstm_kernel(
    const float* __restrict__ feats,
    const float* __restrict__ wih0, const float* __restrict__ whh0,
    const float* __restrict__ bih0, const float* __restrict__ bhh0,
    const float* __restrict__ wih1, const float* __restrict__ whh1,
    const float* __restrict__ bih1, const float* __restrict__ bhh1,
    float* __restrict__ h1o, int* __restrict__ flags,
    float* __restrict__ h2out)
{
    __shared__ __align__(16) float hb[2][64];

    const int tid = threadIdx.x;
    const int role = blockIdx.x >> 4;     // 0 = layer0, 1 = layer1
    const int b = blockIdx.x & 15;
    const int j = tid >> 3;               // h-element 0..63
    const int l = tid & 7;                // K-slice 0..7

    const float4 z4 = make_float4(0.f, 0.f, 0.f, 0.f);
    float4 WH0a = z4, WH0b = z4, WH1a = z4, WH1b = z4,
           WH2a = z4, WH2b = z4, WH3a = z4, WH3b = z4;
    float4 WX0a = z4, WX0b = z4, WX1a = z4, WX1b = z4,
           WX2a = z4, WX2b = z4, WX3a = z4, WX3b = z4;
    float2 xw0 = make_float2(0.f, 0.f), xw1 = xw0, xw2 = xw0, xw3 = xw0;
    float bb0, bb1, bb2, bb3;

    if (role == 0) {
        const float4* p0 = (const float4*)(whh0 + (0 * 64 + j) * 64 + l * 8);
        const float4* p1 = (const float4*)(whh0 + (1 * 64 + j) * 64 + l * 8);
        const float4* p2 = (const float4*)(whh0 + (2 * 64 + j) * 64 + l * 8);
        const float4* p3 = (const float4*)(whh0 + (3 * 64 + j) * 64 + l * 8);
        WH0a = p0[0]; WH0b = p0[1]; WH1a = p1[0]; WH1b = p1[1];
        WH2a = p2[0]; WH2b = p2[1]; WH3a = p3[0]; WH3b = p3[1];
        xw0 = *(const float2*)(wih0 + (0 * 64 + j) * 16 + l * 2);
        xw1 = *(const float2*)(wih0 + (1 * 64 + j) * 16 + l * 2);
        xw2 = *(const float2*)(wih0 + (2 * 64 + j) * 16 + l * 2);
        xw3 = *(const float2*)(wih0 + (3 * 64 + j) * 16 + l * 2);
        bb0 = bih0[j] + bhh0[j];
        bb1 = bih0[64 + j] + bhh0[64 + j];
        bb2 = bih0[128 + j] + bhh0[128 + j];
        bb3 = bih0[192 + j] + bhh0[192 + j];
    } else {
        const float4* q0 = (const float4*)(wih1 + (0 * 64 + j) * 64 + l * 8);
        const float4* q1 = (const float4*)(wih1 + (1 * 64 + j) * 64 + l * 8);
        const float4* q2 = (const float4*)(wih1 + (2 * 64 + j) * 64 + l * 8);
        const float4* q3 = (const float4*)(wih1 + (3 * 64 + j) * 64 + l * 8);
        WX0a = q0[0]; WX0b = q0[1]; WX1a = q1[0]; WX1b = q1[1];
        WX2a = q2[0]; WX2b = q2[1]; WX3a = q3[0]; WX3b = q3[1];
        const float4* p0 = (const float4*)(whh1 + (0 * 64 + j) * 64 + l * 8);
        const float4* p1 = (const float4*)(whh1 + (1 * 64 + j) * 64 + l * 8);
        const float4* p2 = (const float4*)(whh1 + (2 * 64 + j) * 64 + l * 8);
        const float4* p3 = (const float4*)(whh1 + (3 * 64 + j) * 64 + l * 8);
        WH0a = p0[0]; WH0b = p0[1]; WH1a = p1[0]; WH1b = p1[1];
        WH2a = p2[0]; WH2b = p2[1]; WH3a = p3[0]; WH3b = p3[1];
        bb0 = bih1[j] + bhh1[j];
        bb1 = bih1[64 + j] + bhh1[64 + j];
        bb2 = bih1[128 + j] + bhh1[128 + j];
        bb3 = bih1[192 + j] + bhh1[192 + j];
    }

    if (tid < 128) ((float*)hb)[tid] = 0.0f;
    float cst = 0.0f;
    __syncthreads();

    if (role == 0) {
        // ---------------- layer 0 producer ----------------
        const float* fbase = feats + (long)b * 2048 * 16;
        float2 Fc = *(const float2*)(fbase + l * 2);
        for (int s = 0; s < 2048; ++s) {
            const int rp = (s + 1) & 1;
            const int wp = s & 1;
            int sn = (s + 1 < 2048) ? (s + 1) : 2047;
            float2 Fn = *(const float2*)(fbase + sn * 16 + l * 2);  // prefetch
            const float4* hp = (const float4*)&hb[rp][l * 8];
            float4 hv0 = hp[0], hv1 = hp[1];
            float a0 = dot4(WH0b, hv1, dot4(WH0a, hv0, fmaf(xw0.x, Fc.x, xw0.y * Fc.y)));
            float a1 = dot4(WH1b, hv1, dot4(WH1a, hv0, fmaf(xw1.x, Fc.x, xw1.y * Fc.y)));
            float a2 = dot4(WH2b, hv1, dot4(WH2a, hv0, fmaf(xw2.x, Fc.x, xw2.y * Fc.y)));
            float a3 = dot4(WH3b, hv1, dot4(WH3a, hv0, fmaf(xw3.x, Fc.x, xw3.y * Fc.y)));
            a0 += __shfl_xor(a0, 1); a0 += __shfl_xor(a0, 2); a0 += __shfl_xor(a0, 4);
            a1 += __shfl_xor(a1, 1); a1 += __shfl_xor(a1, 2); a1 += __shfl_xor(a1, 4);
            a2 += __shfl_xor(a2, 1); a2 += __shfl_xor(a2, 2); a2 += __shfl_xor(a2, 4);
            a3 += __shfl_xor(a3, 1); a3 += __shfl_xor(a3, 2); a3 += __shfl_xor(a3, 4);
            float gi = sigm(a0 + bb0), gf = sigm(a1 + bb1);
            float gg = tanhfast(a2 + bb2), go = sigm(a3 + bb3);
            cst = fmaf(gf, cst, gi * gg);
            float h = go * tanhfast(cst);
            if (l == 0) {
                hb[wp][j] = h;
                __hip_atomic_store(&h1o[((long)b * 2048 + s) * 64 + j], h,
                                   __ATOMIC_RELAXED, __HIP_MEMORY_SCOPE_AGENT);
            }
            Fc = Fn;
            __syncthreads();   // drains vmcnt on all waves -> h1 stores complete
            if (tid == 0)
                __hip_atomic_store(&flags[b], s + 1,
                                   __ATOMIC_RELEASE, __HIP_MEMORY_SCOPE_AGENT);
        }
    } else {
        // ---------------- layer 1 consumer ----------------
        for (int s = 0; s < 2048; ++s) {
            if (tid == 0) {
                while (__hip_atomic_load(&flags[b], __ATOMIC_ACQUIRE,
                                         __HIP_MEMORY_SCOPE_AGENT) < s + 1) { }
            }
            __syncthreads();   // flag confirmed + L1 invalidated before any h1 read
            const unsigned long long* hp =
                (const unsigned long long*)(h1o + ((long)b * 2048 + s) * 64 + l * 8);
            unsigned long long u0 = __hip_atomic_load(hp + 0, __ATOMIC_RELAXED, __HIP_MEMORY_SCOPE_AGENT);
            unsigned long long u1 = __hip_atomic_load(hp + 1, __ATOMIC_RELAXED, __HIP_MEMORY_SCOPE_AGENT);
            unsigned long long u2 = __hip_atomic_load(hp + 2, __ATOMIC_RELAXED, __HIP_MEMORY_SCOPE_AGENT);
            unsigned long long u3 = __hip_atomic_load(hp + 3, __ATOMIC_RELAXED, __HIP_MEMORY_SCOPE_AGENT);
            float2 f0 = *(float2*)&u0, f1 = *(float2*)&u1, f2 = *(float2*)&u2, f3 = *(float2*)&u3;
            float4 xv0 = make_float4(f0.x, f0.y, f1.x, f1.y);
            float4 xv1 = make_float4(f2.x, f2.y, f3.x, f3.y);
            const float4* hp2 = (const float4*)&hb[s & 1][l * 8];
            float4 hv0 = hp2[0], hv1 = hp2[1];
            float a0 = dot4(WH0b, hv1, dot4(WH0a, hv0, dot4(WX0b, xv1, dot4(WX0a, xv0, 0.f))));
            float a1 = dot4(WH1b, hv1, dot4(WH1a, hv0, dot4(WX1b, xv1, dot4(WX1a, xv0, 0.f))));
            float a2 = dot4(WH2b, hv1, dot4(WH2a, hv0, dot4(WX2b, xv1, dot4(WX2a, xv0, 0.f))));
            float a3 = dot4(WH3b, hv1, dot4(WH3a, hv0, dot4(WX3b, xv1, dot4(WX3a, xv0, 0.f))));
            a0 += __shfl_xor(a0, 1); a0 += __shfl_xor(a0, 2); a0 += __shfl_xor(a0, 4);
            a1 += __shfl_xor(a1, 1); a1 += __shfl_xor(a1, 2); a1 += __shfl_xor(a1, 4);
            a2 += __shfl_xor(a2, 1); a2 += __shfl_xor(a2, 2); a2 += __shfl_xor(a2, 4);
            a3 += __shfl_xor(a3, 1); a3 += __shfl_xor(a3, 2); a3 += __shfl_xor(a3, 4);
            float gi = sigm(a0 + bb0), gf = sigm(a1 + bb1);
            float gg = tanhfast(a2 + bb2), go = sigm(a3 + bb3);
            cst = fmaf(gf, cst, gi * gg);
            float h = go * tanhfast(cst);
            if (l == 0) {
                hb[(s + 1) & 1][j] = h;
                h2out[((long)b * 2048 + s) * 64 + j] = h;
            }
            __syncthreads();
        }
    }
}

// ---------------- FC head ----------------
__global__ __launch_bounds__(256) void fc_kernel(
    const float* __restrict__ h2o,
    const float* __restrict__ fc1w, const float* __restrict__ fc1b,
    const float* __restrict__ fc2w, const float* __restrict__ fc2b,
    float* __restrict__ out)
{
    int r = blockIdx.x * 256 + threadIdx.x;
    float h[64];
    const float4* hp = (const float4*)(h2o + (long)r * 64);
    #pragma unroll
    for (int i = 0; i < 16; ++i) {
        float4 v = hp[i];
        h[4 * i] = v.x; h[4 * i + 1] = v.y; h[4 * i + 2] = v.z; h[4 * i + 3] = v.w;
    }
    float l0 = fc2b[0], l1 = fc2b[1];
    #pragma unroll 4
    for (int j = 0; j < 32; ++j) {
        float z = fc1b[j];
        #pragma unroll
        for (int k = 0; k < 64; ++k) z = fmaf(h[k], fc1w[j * 64 + k], z);
        z = fmaxf(z, 0.0f);
        l0 = fmaf(z, fc2w[j], l0);
        l1 = fmaf(z, fc2w[32 + j], l1);
    }
    out[r * 2] = l0;
    out[r * 2 + 1] = l1;
}

extern "C" void kernel_launch(void* const* d_in, const int* in_sizes, int n_in,
                              void* d_out, int out_size, void* d_ws, size_t ws_size,
                              hipStream_t stream) {
    const float* x    = (const float*)d_in[0];
    const float* w1   = (const float*)d_in[1];
    const float* b1   = (const float*)d_in[2];
    const float* g1   = (const float*)d_in[3];
    const float* be1  = (const float*)d_in[4];
    const float* m1   = (const float*)d_in[5];
    const float* v1   = (const float*)d_in[6];
    const float* w2   = (const float*)d_in[7];
    const float* b2   = (const float*)d_in[8];
    const float* g2   = (const float*)d_in[9];
    const float* be2  = (const float*)d_in[10];
    const float* m2   = (const float*)d_in[11];
    const float* v2   = (const float*)d_in[12];
    const float* w3   = (const float*)d_in[13];
    const float* b3   = (const float*)d_in[14];
    const float* g3   = (const float*)d_in[15];
    const float* be3  = (const float*)d_in[16];
    const float* m3   = (const float*)d_in[17];
    const float* v3   = (const float*)d_in[18];
    const float* wih0 = (const float*)d_in[19];
    const float* whh0 = (const float*)d_in[20];
    const float* bih0 = (const float*)d_in[21];
    const float* bhh0 = (const float*)d_in[22];
    const float* wih1 = (const float*)d_in[23];
    const float* whh1 = (const float*)d_in[24];
    const float* bih1 = (const float*)d_in[25];
    const float* bhh1 = (const float*)d_in[26];
    const float* fc1w = (const float*)d_in[27];
    const float* fc1b = (const float*)d_in[28];
    const float* fc2w = (const float*)d_in[29];
    const float* fc2b = (const float*)d_in[30];
    float* out = (float*)d_out;

    float* ws    = (float*)d_ws;
    float* feats = ws;                            // 524288 floats
    float* h2o   = ws + 32768 * 16;               // 2097152 floats
    float* w2t2  = h2o + 32768 * 64;              // 16384 floats
    float* w3p4f = w2t2 + 16384;                  // 2048 floats (512 float4)
    float* w3p1  = w3p4f + 2048;                  // 512 floats
    float* h1o   = w3p1 + 512;                    // 2097152 floats
    int*   flags = (int*)(h1o + 32768 * 64);      // 16 ints

    hipLaunchKernelGGL(pack_kernel, dim3(67), dim3(256), 0, stream,
                       w2, w3, w2t2, (float4*)w3p4f, w3p1, flags);
    hipLaunchKernelGGL(cnn_kernel, dim3(32768), dim3(256), 0, stream,
                       x, w1, b1, g1, be1, m1, v1, b2, g2, be2, m2, v2,
                       b3, g3, be3, m3, v3, w2t2, (const float4*)w3p4f, w3p1, feats);
    hipLaunchKernelGGL(lstm_kernel, dim3(32), dim3(512), 0, stream,
                       feats, wih0, whh0, bih0, bhh0, wih1, whh1, bih1, bhh1,
                       h1o, flags, h2o);
    hipLaunchKernelGGL(fc_kernel, dim3(128), dim3(256), 0, stream,
                       h2o, fc1w, fc1b, fc2w, fc2b, out);
}

// Round 6
// 2857.492 us; speedup vs baseline: 1.3992x; 1.3992x over previous
//
#include <hip/hip_runtime.h>

#define EPSV 1e-5f

__device__ __forceinline__ float fast_rcp(float x) { return __builtin_amdgcn_rcpf(x); }
__device__ __forceinline__ float sigm(float x) { return fast_rcp(1.0f + __expf(-x)); }
__device__ __forceinline__ float tanhfast(float x) {
    float e = __expf(2.0f * x);
    return 1.0f - 2.0f * fast_rcp(e + 1.0f);
}
__device__ __forceinline__ float dot4(const float4 w, const float4 v, float a) {
    a = fmaf(w.x, v.x, a);
    a = fmaf(w.y, v.y, a);
    a = fmaf(w.z, v.z, a);
    a = fmaf(w.w, v.w, a);
    return a;
}

// ------- pack: w2 -> w2t2[(i*32+o)*8+k]; w3 -> w3p4/w3p1[(i*16+o)] -------
__global__ void pack_kernel(const float* __restrict__ w2, const float* __restrict__ w3,
                            float* __restrict__ w2t2, float4* __restrict__ w3p4,
                            float* __restrict__ w3p1) {
    int j = blockIdx.x * 256 + threadIdx.x;
    if (j < 16384) {
        int i = j >> 8;
        int o = (j >> 3) & 31;
        int k = j & 7;
        w2t2[j] = (k < 7) ? w2[o * 448 + i * 7 + k] : 0.0f;
    } else if (j < 16896) {
        int e = j - 16384;            // e = i*16+o
        int i = e >> 4, o = e & 15;
        int base = o * 160 + i * 5;
        w3p4[e] = make_float4(w3[base], w3[base + 1], w3[base + 2], w3[base + 3]);
        w3p1[e] = w3[base + 4];
    }
}

// ---------------- CNN: one block per window (b,t) ---------------- (unchanged)
__global__ __launch_bounds__(256) void cnn_kernel(
    const float* __restrict__ x,
    const float* __restrict__ w1, const float* __restrict__ b1,
    const float* __restrict__ g1, const float* __restrict__ be1,
    const float* __restrict__ m1, const float* __restrict__ v1,
    const float* __restrict__ b2,
    const float* __restrict__ g2, const float* __restrict__ be2,
    const float* __restrict__ m2, const float* __restrict__ v2,
    const float* __restrict__ b3,
    const float* __restrict__ g3, const float* __restrict__ be3,
    const float* __restrict__ m3, const float* __restrict__ v3,
    const float* __restrict__ w2t2,
    const float4* __restrict__ w3p4, const float* __restrict__ w3p1,
    float* __restrict__ feats)
{
    __shared__ float winh[64];
    __shared__ float w1t[9 * 64];
    __shared__ __align__(16) float a1[64 * 84 + 32];
    __shared__ __align__(16) float a2[32 * 56 + 16];
    __shared__ float s1[64], t1[64], s2[32], t2[32], s3[16], t3[16];
    __shared__ float psum[16 * 16];

    const int tid = threadIdx.x;
    const int w = blockIdx.x;
    const int b = w >> 11;
    const int t = w & 2047;

    for (int idx = tid; idx < 576; idx += 256) {
        int o = idx / 9, k = idx % 9;
        w1t[k * 64 + o] = w1[idx];
    }
    if (tid < 64) {
        float s = g1[tid] * rsqrtf(v1[tid] + EPSV);
        s1[tid] = s;
        t1[tid] = (b1[tid] - m1[tid]) * s + be1[tid];
    } else if (tid < 96) {
        int o = tid - 64;
        float s = g2[o] * rsqrtf(v2[o] + EPSV);
        s2[o] = s;
        t2[o] = (b2[o] - m2[o]) * s + be2[o];
    } else if (tid < 112) {
        int o = tid - 96;
        float s = g3[o] * rsqrtf(v3[o] + EPSV);
        s3[o] = s;
        t3[o] = (b3[o] - m3[o]) * s + be3[o];
    }
    if (tid < 64) {
        winh[tid] = 0.0f;
        float* r = &a1[tid * 84];
        r[0] = 0.f; r[1] = 0.f; r[2] = 0.f;
        r[77] = 0.f; r[78] = 0.f; r[79] = 0.f;
    }
    if (tid < 32) {
        float* r = &a2[tid * 56];
        r[0] = 0.f; r[1] = 0.f;
        r[52] = 0.f; r[53] = 0.f; r[54] = 0.f; r[55] = 0.f;
    }
    __syncthreads();
    if (tid < 50) {
        int gi = t + tid - 49;
        winh[4 + tid] = (gi >= 0) ? x[b * 2048 + gi] : 0.0f;
    }
    __syncthreads();

    {   // conv1
        int o = tid >> 2, pg = tid & 3;
        int p0 = pg * 13;
        float wv[9];
        #pragma unroll
        for (int k = 0; k < 9; ++k) wv[k] = w1t[k * 64 + o];
        float sc = s1[o], tc = t1[o];
        #pragma unroll
        for (int q = 0; q < 13; ++q) {
            int p = p0 + q;
            if (p < 50) {
                float acc = 0.0f;
                #pragma unroll
                for (int k = 0; k < 9; ++k) acc = fmaf(wv[k], winh[p + k], acc);
                int pi = p + 3;
                int slot = pi + ((pi >> 3) << 2);
                a1[o * 84 + slot] = fmaxf(acc * sc + tc, 0.0f);
            }
        }
    }
    __syncthreads();

    {   // conv2
        int o = tid >> 3, pg = tid & 7;
        float acc[8];
        #pragma unroll
        for (int q = 0; q < 8; ++q) acc[q] = 0.0f;
        for (int i = 0; i < 64; ++i) {
            const float* rowp = &a1[i * 84 + 12 * pg];
            float4 A0 = *(const float4*)&rowp[0];
            float4 A1 = *(const float4*)&rowp[4];
            float4 A2 = *(const float4*)&rowp[12];
            float2 A3 = *(const float2*)&rowp[16];
            const float4* wp = (const float4*)&w2t2[(i * 32 + o) * 8];
            float4 Wa = wp[0], Wb = wp[1];
            float av[14] = {A0.x, A0.y, A0.z, A0.w, A1.x, A1.y, A1.z, A1.w,
                            A2.x, A2.y, A2.z, A2.w, A3.x, A3.y};
            float wk[7] = {Wa.x, Wa.y, Wa.z, Wa.w, Wb.x, Wb.y, Wb.z};
            #pragma unroll
            for (int k = 0; k < 7; ++k) {
                #pragma unroll
                for (int q = 0; q < 8; ++q) acc[q] = fmaf(wk[k], av[q + k], acc[q]);
            }
        }
        float sc = s2[o], tc = t2[o];
        float r[8];
        #pragma unroll
        for (int q = 0; q < 8; ++q) r[q] = fmaxf(acc[q] * sc + tc, 0.0f);
        float* row = &a2[o * 56 + 8 * pg];
        if (pg < 6) {
            *(float2*)&row[2] = make_float2(r[0], r[1]);
            *(float4*)&row[4] = make_float4(r[2], r[3], r[4], r[5]);
            *(float2*)&row[8] = make_float2(r[6], r[7]);
        } else if (pg == 6) {
            *(float2*)&row[2] = make_float2(r[0], r[1]);
        }
    }
    __syncthreads();

    {   // conv3 + mean partials
        int o = tid & 15, pg = tid >> 4;
        float acc[4];
        #pragma unroll
        for (int q = 0; q < 4; ++q) acc[q] = 0.0f;
        for (int i = 0; i < 32; ++i) {
            float4 wa = w3p4[i * 16 + o];
            float w4 = w3p1[i * 16 + o];
            const float4* ap = (const float4*)&a2[i * 56 + 4 * pg];
            float4 Aa = ap[0], Ab = ap[1];
            float av[8] = {Aa.x, Aa.y, Aa.z, Aa.w, Ab.x, Ab.y, Ab.z, Ab.w};
            #pragma unroll
            for (int q = 0; q < 4; ++q) {
                acc[q] = fmaf(wa.x, av[q], acc[q]);
                acc[q] = fmaf(wa.y, av[q + 1], acc[q]);
                acc[q] = fmaf(wa.z, av[q + 2], acc[q]);
                acc[q] = fmaf(wa.w, av[q + 3], acc[q]);
                acc[q] = fmaf(w4,   av[q + 4], acc[q]);
            }
        }
        float sc = s3[o], tc = t3[o];
        float ps = 0.0f;
        #pragma unroll
        for (int q = 0; q < 4; ++q) {
            int p = 4 * pg + q;
            if (p < 50) ps += fmaxf(acc[q] * sc + tc, 0.0f);
        }
        psum[pg * 16 + o] = ps;
    }
    __syncthreads();

    if (tid < 16) {
        float s = 0.0f;
        #pragma unroll
        for (int pg = 0; pg < 16; ++pg) s += psum[pg * 16 + tid];
        feats[w * 16 + tid] = s * (1.0f / 50.0f);
    }
}

// ---------------- LSTM phase 0: 16 blocks x 512 threads, layer 0 only ----------------
// tid = j*8 + gt*2 + hf : element j (0..63), gate gt (i,f,g,o), K-half hf.
// Per step: 8 dot4 (recurrent half) + 2 dot4 (x, K=16 half from LDS-staged feats chunk),
// butterfly shfl reduce, branchless activation, update lanes (tid%8==0) own c.
// h-seq buffered in LDS ring, flushed to global every 16 steps -> per-step barrier has
// no outstanding vmem to drain (the __syncthreads vmcnt(0) gotcha).
__global__ __launch_bounds__(512, 2) void lstm0_kernel(
    const float* __restrict__ feats,
    const float* __restrict__ wih0, const float* __restrict__ whh0,
    const float* __restrict__ bih0, const float* __restrict__ bhh0,
    float* __restrict__ h1o)
{
    __shared__ __align__(16) float hbuf[2][64];
    __shared__ __align__(16) float ring[2][16][64];
    __shared__ __align__(16) float fst[256];

    const int tid = threadIdx.x;
    const int b = blockIdx.x;
    const int j = tid >> 3;
    const int gt = (tid >> 1) & 3;
    const int hf = tid & 1;
    const int row = gt * 64 + j;
    const float m_ = (gt == 2) ? 2.0f : 1.0f;   // act = 1 - m*rcp(exp(m*x)+1): m=1 sigm, m=2 tanh

    const float4* wh = (const float4*)(whh0 + row * 64 + hf * 32);
    float4 W0 = wh[0], W1 = wh[1], W2 = wh[2], W3 = wh[3],
           W4 = wh[4], W5 = wh[5], W6 = wh[6], W7 = wh[7];
    const float4* wx = (const float4*)(wih0 + row * 16 + hf * 8);
    float4 X0 = wx[0], X1 = wx[1];
    const float bb = bih0[row] + bhh0[row];

    if (tid < 64) hbuf[1][tid] = 0.0f;
    float cst = 0.0f;
    __syncthreads();

    for (int c = 0; c < 128; ++c) {
        if (c > 0) {   // flush previous chunk's ring (stores drain at the next barrier only)
            float2 v = ((const float2*)ring[(c - 1) & 1])[tid];
            *(float2*)&h1o[((long)b * 2048 + (c - 1) * 16) * 64 + tid * 2] = v;
        }
        if (tid < 256) fst[tid] = feats[(long)b * 32768 + c * 256 + tid];
        __syncthreads();
        float (* __restrict__ rw)[64] = ring[c & 1];
        #pragma unroll
        for (int k = 0; k < 16; ++k) {
            const float4* hp = (const float4*)&hbuf[(k + 1) & 1][hf * 32];
            const float4* fp = (const float4*)&fst[k * 16 + hf * 8];
            float a = 0.f, a2 = 0.f;
            a  = dot4(W0, hp[0], a);  a2 = dot4(W1, hp[1], a2);
            a  = dot4(W2, hp[2], a);  a2 = dot4(W3, hp[3], a2);
            a  = dot4(W4, hp[4], a);  a2 = dot4(W5, hp[5], a2);
            a  = dot4(W6, hp[6], a);  a2 = dot4(W7, hp[7], a2);
            a  = dot4(X0, fp[0], a);  a2 = dot4(X1, fp[1], a2);
            float part = a + a2;
            float tot = part + __shfl_xor(part, 1) + bb;
            float act = 1.0f - m_ * fast_rcp(__expf(m_ * tot) + 1.0f);
            float v1 = __shfl_xor(act, 2);
            float v2 = __shfl_xor(act, 4);
            float v3 = __shfl_xor(act, 6);
            if ((tid & 7) == 0) {      // act=i, v1=f, v2=g, v3=o
                cst = fmaf(v1, cst, act * v2);
                float h = v3 * tanhfast(cst);
                hbuf[k & 1][j] = h;
                rw[k][j] = h;
            }
            __syncthreads();
        }
    }
    {   // final flush
        float2 v = ((const float2*)ring[1])[tid];   // chunk 127 parity = 1
        *(float2*)&h1o[((long)b * 2048 + 127 * 16) * 64 + tid * 2] = v;
    }
}

// ---------------- pre1 GEMM: preT[(b*256+row)*2048 + t] = h1(t) . wih1[row] + bias ----------------
// block = (b, 16-step t-chunk); 256 threads, one gate-row each; writes 64B/thread contiguous.
__global__ __launch_bounds__(256) void pre1_gemm_kernel(
    const float* __restrict__ h1o, const float* __restrict__ wih1,
    const float* __restrict__ bih1, const float* __restrict__ bhh1,
    float* __restrict__ preT)
{
    __shared__ __align__(16) float hst[16][64];
    const int tid = threadIdx.x;
    const int blk = blockIdx.x;
    const int b = blk >> 7;
    const int t0 = (blk & 127) * 16;

    {
        int tt = tid >> 4, kq = tid & 15;
        *(float4*)&hst[tt][kq * 4] =
            *(const float4*)&h1o[((long)b * 2048 + t0 + tt) * 64 + kq * 4];
    }
    __syncthreads();

    const int row = tid;
    float4 W[16];
    const float4* wp = (const float4*)(wih1 + row * 64);
    #pragma unroll
    for (int q = 0; q < 16; ++q) W[q] = wp[q];
    const float bias = bih1[row] + bhh1[row];

    float outv[16];
    #pragma unroll
    for (int tt = 0; tt < 16; ++tt) {
        const float4* hp = (const float4*)hst[tt];
        float a = 0.f, a2 = 0.f;
        #pragma unroll
        for (int q = 0; q < 16; q += 2) {
            a  = dot4(W[q], hp[q], a);
            a2 = dot4(W[q + 1], hp[q + 1], a2);
        }
        outv[tt] = a + a2 + bias;
    }
    float* op = preT + ((long)b * 256 + row) * 2048 + t0;
    #pragma unroll
    for (int q = 0; q < 4; ++q)
        *(float4*)&op[q * 4] = make_float4(outv[4 * q], outv[4 * q + 1],
                                           outv[4 * q + 2], outv[4 * q + 3]);
}

// ---------------- LSTM phase 1: 16 blocks x 512 threads, layer 1, pre in registers ----------------
__global__ __launch_bounds__(512, 2) void lstm1_kernel(
    const float* __restrict__ preT, const float* __restrict__ whh1,
    float* __restrict__ h2o)
{
    __shared__ __align__(16) float hbuf[2][64];
    __shared__ __align__(16) float ring[2][16][64];

    const int tid = threadIdx.x;
    const int b = blockIdx.x;
    const int j = tid >> 3;
    const int gt = (tid >> 1) & 3;
    const int hf = tid & 1;
    const int row = gt * 64 + j;
    const float m_ = (gt == 2) ? 2.0f : 1.0f;

    const float4* wh = (const float4*)(whh1 + row * 64 + hf * 32);
    float4 W0 = wh[0], W1 = wh[1], W2 = wh[2], W3 = wh[3],
           W4 = wh[4], W5 = wh[5], W6 = wh[6], W7 = wh[7];

    const float* pbase = preT + ((long)b * 256 + row) * 2048;

    float pc[16], pn[16];
    {   // first chunk loaded directly
        const float4* pp = (const float4*)pbase;
        #pragma unroll
        for (int q = 0; q < 4; ++q) {
            float4 v = pp[q];
            pc[4 * q] = v.x; pc[4 * q + 1] = v.y; pc[4 * q + 2] = v.z; pc[4 * q + 3] = v.w;
        }
    }

    if (tid < 64) hbuf[1][tid] = 0.0f;
    float cst = 0.0f;
    __syncthreads();

    for (int c = 0; c < 128; ++c) {
        if (c > 0) {
            float2 v = ((const float2*)ring[(c - 1) & 1])[tid];
            *(float2*)&h2o[((long)b * 2048 + (c - 1) * 16) * 64 + tid * 2] = v;
        }
        if (c < 127) {   // prefetch next chunk (drains at first step's barrier, amortized)
            const float4* pp = (const float4*)(pbase + (c + 1) * 16);
            #pragma unroll
            for (int q = 0; q < 4; ++q) {
                float4 v = pp[q];
                pn[4 * q] = v.x; pn[4 * q + 1] = v.y; pn[4 * q + 2] = v.z; pn[4 * q + 3] = v.w;
            }
        }
        __syncthreads();
        float (* __restrict__ rw)[64] = ring[c & 1];
        #pragma unroll
        for (int k = 0; k < 16; ++k) {
            const float4* hp = (const float4*)&hbuf[(k + 1) & 1][hf * 32];
            float a = 0.f, a2 = 0.f;
            a  = dot4(W0, hp[0], a);  a2 = dot4(W1, hp[1], a2);
            a  = dot4(W2, hp[2], a);  a2 = dot4(W3, hp[3], a2);
            a  = dot4(W4, hp[4], a);  a2 = dot4(W5, hp[5], a2);
            a  = dot4(W6, hp[6], a);  a2 = dot4(W7, hp[7], a2);
            float part = a + a2;
            float tot = part + __shfl_xor(part, 1) + pc[k];
            float act = 1.0f - m_ * fast_rcp(__expf(m_ * tot) + 1.0f);
            float v1 = __shfl_xor(act, 2);
            float v2 = __shfl_xor(act, 4);
            float v3 = __shfl_xor(act, 6);
            if ((tid & 7) == 0) {
                cst = fmaf(v1, cst, act * v2);
                float h = v3 * tanhfast(cst);
                hbuf[k & 1][j] = h;
                rw[k][j] = h;
            }
            __syncthreads();
        }
        #pragma unroll
        for (int q = 0; q < 16; ++q) pc[q] = pn[q];
    }
    {
        float2 v = ((const float2*)ring[1])[tid];
        *(float2*)&h2o[((long)b * 2048 + 127 * 16) * 64 + tid * 2] = v;
    }
}

// ---------------- FC head ----------------
__global__ __launch_bounds__(256) void fc_kernel(
    const float* __restrict__ h2o,
    const float* __restrict__ fc1w, const float* __restrict__ fc1b,
    const float* __restrict__ fc2w, const float* __restrict__ fc2b,
    float* __restrict__ out)
{
    int r = blockIdx.x * 256 + threadIdx.x;
    float h[64];
    const float4* hp = (const float4*)(h2o + (long)r * 64);
    #pragma unroll
    for (int i = 0; i < 16; ++i) {
        float4 v = hp[i];
        h[4 * i] = v.x; h[4 * i + 1] = v.y; h[4 * i + 2] = v.z; h[4 * i + 3] = v.w;
    }
    float l0 = fc2b[0], l1 = fc2b[1];
    #pragma unroll 4
    for (int j = 0; j < 32; ++j) {
        float z = fc1b[j];
        #pragma unroll
        for (int k = 0; k < 64; ++k) z = fmaf(h[k], fc1w[j * 64 + k], z);
        z = fmaxf(z, 0.0f);
        l0 = fmaf(z, fc2w[j], l0);
        l1 = fmaf(z, fc2w[32 + j], l1);
    }
    out[r * 2] = l0;
    out[r * 2 + 1] = l1;
}

extern "C" void kernel_launch(void* const* d_in, const int* in_sizes, int n_in,
                              void* d_out, int out_size, void* d_ws, size_t ws_size,
                              hipStream_t stream) {
    const float* x    = (const float*)d_in[0];
    const float* w1   = (const float*)d_in[1];
    const float* b1   = (const float*)d_in[2];
    const float* g1   = (const float*)d_in[3];
    const float* be1  = (const float*)d_in[4];
    const float* m1   = (const float*)d_in[5];
    const float* v1   = (const float*)d_in[6];
    const float* w2   = (const float*)d_in[7];
    const float* b2   = (const float*)d_in[8];
    const float* g2   = (const float*)d_in[9];
    const float* be2  = (const float*)d_in[10];
    const float* m2   = (const float*)d_in[11];
    const float* v2   = (const float*)d_in[12];
    const float* w3   = (const float*)d_in[13];
    const float* b3   = (const float*)d_in[14];
    const float* g3   = (const float*)d_in[15];
    const float* be3  = (const float*)d_in[16];
    const float* m3   = (const float*)d_in[17];
    const float* v3   = (const float*)d_in[18];
    const float* wih0 = (const float*)d_in[19];
    const float* whh0 = (const float*)d_in[20];
    const float* bih0 = (const float*)d_in[21];
    const float* bhh0 = (const float*)d_in[22];
    const float* wih1 = (const float*)d_in[23];
    const float* whh1 = (const float*)d_in[24];
    const float* bih1 = (const float*)d_in[25];
    const float* bhh1 = (const float*)d_in[26];
    const float* fc1w = (const float*)d_in[27];
    const float* fc1b = (const float*)d_in[28];
    const float* fc2w = (const float*)d_in[29];
    const float* fc2b = (const float*)d_in[30];
    float* out = (float*)d_out;

    float* ws    = (float*)d_ws;
    float* feats = ws;                            // 524288 floats
    float* h2o   = feats + 32768 * 16;            // 2097152 floats
    float* w2t2  = h2o + 32768 * 64;              // 16384 floats
    float* w3p4f = w2t2 + 16384;                  // 2048 floats
    float* w3p1  = w3p4f + 2048;                  // 512 floats
    float* h1o   = w3p1 + 512;                    // 2097152 floats
    float* preT  = h1o + 32768 * 64;              // 8388608 floats (32 MB)

    hipLaunchKernelGGL(pack_kernel, dim3(66), dim3(256), 0, stream,
                       w2, w3, w2t2, (float4*)w3p4f, w3p1);
    hipLaunchKernelGGL(cnn_kernel, dim3(32768), dim3(256), 0, stream,
                       x, w1, b1, g1, be1, m1, v1, b2, g2, be2, m2, v2,
                       b3, g3, be3, m3, v3, w2t2, (const float4*)w3p4f, w3p1, feats);
    hipLaunchKernelGGL(lstm0_kernel, dim3(16), dim3(512), 0, stream,
                       feats, wih0, whh0, bih0, bhh0, h1o);
    hipLaunchKernelGGL(pre1_gemm_kernel, dim3(2048), dim3(256), 0, stream,
                       h1o, wih1, bih1, bhh1, preT);
    hipLaunchKernelGGL(lstm1_kernel, dim3(16), dim3(512), 0, stream,
                       preT, whh1, h2o);
    hipLaunchKernelGGL(fc_kernel, dim3(128), dim3(256), 0, stream,
                       h2o, fc1w, fc1b, fc2w, fc2b, out);
}

// Round 7
// 2759.294 us; speedup vs baseline: 1.4490x; 1.0356x over previous
//
#include <hip/hip_runtime.h>

#define EPSV 1e-5f

__device__ __forceinline__ float fast_rcp(float x) { return __builtin_amdgcn_rcpf(x); }
__device__ __forceinline__ float tanhfast(float x) {
    float e = __expf(2.0f * x);
    return 1.0f - 2.0f * fast_rcp(e + 1.0f);
}
__device__ __forceinline__ float dot4(const float4 w, const float4 v, float a) {
    a = fmaf(w.x, v.x, a);
    a = fmaf(w.y, v.y, a);
    a = fmaf(w.z, v.z, a);
    a = fmaf(w.w, v.w, a);
    return a;
}

// DPP helpers (quad_perm; ctrl must be a literal/ICE at each use site)
#define DPPF(v, ctrl) __int_as_float(__builtin_amdgcn_mov_dpp(__float_as_int(v), (ctrl), 0xF, 0xF, false))

// ------- pack: w2 -> w2t2[(i*32+o)*8+k]; w3 -> w3p4/w3p1[(i*16+o)] -------
__global__ void pack_kernel(const float* __restrict__ w2, const float* __restrict__ w3,
                            float* __restrict__ w2t2, float4* __restrict__ w3p4,
                            float* __restrict__ w3p1) {
    int j = blockIdx.x * 256 + threadIdx.x;
    if (j < 16384) {
        int i = j >> 8;
        int o = (j >> 3) & 31;
        int k = j & 7;
        w2t2[j] = (k < 7) ? w2[o * 448 + i * 7 + k] : 0.0f;
    } else if (j < 16896) {
        int e = j - 16384;            // e = i*16+o
        int i = e >> 4, o = e & 15;
        int base = o * 160 + i * 5;
        w3p4[e] = make_float4(w3[base], w3[base + 1], w3[base + 2], w3[base + 3]);
        w3p1[e] = w3[base + 4];
    }
}

// ---------------- CNN: one block per window (b,t) ---------------- (unchanged)
__global__ __launch_bounds__(256) void cnn_kernel(
    const float* __restrict__ x,
    const float* __restrict__ w1, const float* __restrict__ b1,
    const float* __restrict__ g1, const float* __restrict__ be1,
    const float* __restrict__ m1, const float* __restrict__ v1,
    const float* __restrict__ b2,
    const float* __restrict__ g2, const float* __restrict__ be2,
    const float* __restrict__ m2, const float* __restrict__ v2,
    const float* __restrict__ b3,
    const float* __restrict__ g3, const float* __restrict__ be3,
    const float* __restrict__ m3, const float* __restrict__ v3,
    const float* __restrict__ w2t2,
    const float4* __restrict__ w3p4, const float* __restrict__ w3p1,
    float* __restrict__ feats)
{
    __shared__ float winh[64];
    __shared__ float w1t[9 * 64];
    __shared__ __align__(16) float a1[64 * 84 + 32];
    __shared__ __align__(16) float a2[32 * 56 + 16];
    __shared__ float s1[64], t1[64], s2[32], t2[32], s3[16], t3[16];
    __shared__ float psum[16 * 16];

    const int tid = threadIdx.x;
    const int w = blockIdx.x;
    const int b = w >> 11;
    const int t = w & 2047;

    for (int idx = tid; idx < 576; idx += 256) {
        int o = idx / 9, k = idx % 9;
        w1t[k * 64 + o] = w1[idx];
    }
    if (tid < 64) {
        float s = g1[tid] * rsqrtf(v1[tid] + EPSV);
        s1[tid] = s;
        t1[tid] = (b1[tid] - m1[tid]) * s + be1[tid];
    } else if (tid < 96) {
        int o = tid - 64;
        float s = g2[o] * rsqrtf(v2[o] + EPSV);
        s2[o] = s;
        t2[o] = (b2[o] - m2[o]) * s + be2[o];
    } else if (tid < 112) {
        int o = tid - 96;
        float s = g3[o] * rsqrtf(v3[o] + EPSV);
        s3[o] = s;
        t3[o] = (b3[o] - m3[o]) * s + be3[o];
    }
    if (tid < 64) {
        winh[tid] = 0.0f;
        float* r = &a1[tid * 84];
        r[0] = 0.f; r[1] = 0.f; r[2] = 0.f;
        r[77] = 0.f; r[78] = 0.f; r[79] = 0.f;
    }
    if (tid < 32) {
        float* r = &a2[tid * 56];
        r[0] = 0.f; r[1] = 0.f;
        r[52] = 0.f; r[53] = 0.f; r[54] = 0.f; r[55] = 0.f;
    }
    __syncthreads();
    if (tid < 50) {
        int gi = t + tid - 49;
        winh[4 + tid] = (gi >= 0) ? x[b * 2048 + gi] : 0.0f;
    }
    __syncthreads();

    {   // conv1
        int o = tid >> 2, pg = tid & 3;
        int p0 = pg * 13;
        float wv[9];
        #pragma unroll
        for (int k = 0; k < 9; ++k) wv[k] = w1t[k * 64 + o];
        float sc = s1[o], tc = t1[o];
        #pragma unroll
        for (int q = 0; q < 13; ++q) {
            int p = p0 + q;
            if (p < 50) {
                float acc = 0.0f;
                #pragma unroll
                for (int k = 0; k < 9; ++k) acc = fmaf(wv[k], winh[p + k], acc);
                int pi = p + 3;
                int slot = pi + ((pi >> 3) << 2);
                a1[o * 84 + slot] = fmaxf(acc * sc + tc, 0.0f);
            }
        }
    }
    __syncthreads();

    {   // conv2
        int o = tid >> 3, pg = tid & 7;
        float acc[8];
        #pragma unroll
        for (int q = 0; q < 8; ++q) acc[q] = 0.0f;
        for (int i = 0; i < 64; ++i) {
            const float* rowp = &a1[i * 84 + 12 * pg];
            float4 A0 = *(const float4*)&rowp[0];
            float4 A1 = *(const float4*)&rowp[4];
            float4 A2 = *(const float4*)&rowp[12];
            float2 A3 = *(const float2*)&rowp[16];
            const float4* wp = (const float4*)&w2t2[(i * 32 + o) * 8];
            float4 Wa = wp[0], Wb = wp[1];
            float av[14] = {A0.x, A0.y, A0.z, A0.w, A1.x, A1.y, A1.z, A1.w,
                            A2.x, A2.y, A2.z, A2.w, A3.x, A3.y};
            float wk[7] = {Wa.x, Wa.y, Wa.z, Wa.w, Wb.x, Wb.y, Wb.z};
            #pragma unroll
            for (int k = 0; k < 7; ++k) {
                #pragma unroll
                for (int q = 0; q < 8; ++q) acc[q] = fmaf(wk[k], av[q + k], acc[q]);
            }
        }
        float sc = s2[o], tc = t2[o];
        float r[8];
        #pragma unroll
        for (int q = 0; q < 8; ++q) r[q] = fmaxf(acc[q] * sc + tc, 0.0f);
        float* row = &a2[o * 56 + 8 * pg];
        if (pg < 6) {
            *(float2*)&row[2] = make_float2(r[0], r[1]);
            *(float4*)&row[4] = make_float4(r[2], r[3], r[4], r[5]);
            *(float2*)&row[8] = make_float2(r[6], r[7]);
        } else if (pg == 6) {
            *(float2*)&row[2] = make_float2(r[0], r[1]);
        }
    }
    __syncthreads();

    {   // conv3 + mean partials
        int o = tid & 15, pg = tid >> 4;
        float acc[4];
        #pragma unroll
        for (int q = 0; q < 4; ++q) acc[q] = 0.0f;
        for (int i = 0; i < 32; ++i) {
            float4 wa = w3p4[i * 16 + o];
            float w4 = w3p1[i * 16 + o];
            const float4* ap = (const float4*)&a2[i * 56 + 4 * pg];
            float4 Aa = ap[0], Ab = ap[1];
            float av[8] = {Aa.x, Aa.y, Aa.z, Aa.w, Ab.x, Ab.y, Ab.z, Ab.w};
            #pragma unroll
            for (int q = 0; q < 4; ++q) {
                acc[q] = fmaf(wa.x, av[q], acc[q]);
                acc[q] = fmaf(wa.y, av[q + 1], acc[q]);
                acc[q] = fmaf(wa.z, av[q + 2], acc[q]);
                acc[q] = fmaf(wa.w, av[q + 3], acc[q]);
                acc[q] = fmaf(w4,   av[q + 4], acc[q]);
            }
        }
        float sc = s3[o], tc = t3[o];
        float ps = 0.0f;
        #pragma unroll
        for (int q = 0; q < 4; ++q) {
            int p = 4 * pg + q;
            if (p < 50) ps += fmaxf(acc[q] * sc + tc, 0.0f);
        }
        psum[pg * 16 + o] = ps;
    }
    __syncthreads();

    if (tid < 16) {
        float s = 0.0f;
        #pragma unroll
        for (int pg = 0; pg < 16; ++pg) s += psum[pg * 16 + tid];
        feats[w * 16 + tid] = s * (1.0f / 50.0f);
    }
}

// ------- pre GEMM: pre[(b*2048+t)*256 + j*4+g] = wih[g*64+j] . x(b,t) + bih+bhh -------
template<int KDIM>
__global__ __launch_bounds__(256) void pre_gemm_kernel(
    const float* __restrict__ xin,   // (b*2048+t)*KDIM
    const float* __restrict__ wih,   // (256, KDIM)
    const float* __restrict__ bih, const float* __restrict__ bhh,
    float* __restrict__ pre)
{
    __shared__ __align__(16) float xst[16 * KDIM];
    const int tid = threadIdx.x;
    const int blk = blockIdx.x;
    const int b = blk >> 7;
    const int t0 = (blk & 127) * 16;

    for (int e = tid; e < 16 * KDIM; e += 256) {
        int tt = e / KDIM, kk = e % KDIM;
        xst[e] = xin[((long)b * 2048 + t0 + tt) * KDIM + kk];
    }
    const int j = tid >> 2, g = tid & 3;
    const int row = g * 64 + j;
    float4 W[KDIM / 4];
    const float4* wp = (const float4*)(wih + row * KDIM);
    #pragma unroll
    for (int q = 0; q < KDIM / 4; ++q) W[q] = wp[q];
    const float bias = bih[row] + bhh[row];
    __syncthreads();
    #pragma unroll
    for (int tt = 0; tt < 16; ++tt) {
        const float4* xp = (const float4*)&xst[tt * KDIM];
        float a = 0.f, a2 = 0.f;
        #pragma unroll
        for (int q = 0; q < KDIM / 4; q += 2) {
            a = dot4(W[q], xp[q], a);
            if (q + 1 < KDIM / 4) a2 = dot4(W[q + 1], xp[q + 1], a2);
        }
        pre[((long)b * 2048 + t0 + tt) * 256 + tid] = a + a2 + bias;
    }
}

// ---------------- LSTM recurrence: 16 blocks x 256 threads ----------------
// Quad per h-element j: lane kq in [0,4) computes partials of ALL 4 gates over K-slice
// [kq*16, kq*16+16). Only 4 ds_read_b128 per lane per step (4x less DS-pipe than round 6).
// Quad xor-butterfly via DPP quad_perm (VALU, no LDS): every lane gets all 4 gate totals,
// does the c-update redundantly (bitwise identical). Pre-activations (W_ih.x + biases,
// from pre_gemm) register-prefetched per 16-step chunk (lane kq holds steps kq*4..kq*4+3),
// quad-broadcast by DPP at each step. One barrier/step; global ops only at chunk edges.
__global__ __launch_bounds__(256, 1) void lstm_rec_kernel(
    const float* __restrict__ pre,   // (b*2048+t)*256 + j*4+g
    const float* __restrict__ whh,   // (256, 64), rows g*64+j
    float* __restrict__ hout)        // (b*2048+t)*64 + j
{
    __shared__ __align__(16) float hbuf[2][64];
    __shared__ __align__(16) float ring[2][16][64];

    const int tid = threadIdx.x;
    const int b = blockIdx.x;
    const int j = tid >> 2;
    const int kq = tid & 3;

    // recurrent weights: 4 gates x K-slice kq (16 floats each) in named regs
    const float4* wpa = (const float4*)(whh + (0 * 64 + j) * 64 + kq * 16);
    const float4* wpb = (const float4*)(whh + (1 * 64 + j) * 64 + kq * 16);
    const float4* wpc = (const float4*)(whh + (2 * 64 + j) * 64 + kq * 16);
    const float4* wpd = (const float4*)(whh + (3 * 64 + j) * 64 + kq * 16);
    float4 A0 = wpa[0], A1 = wpa[1], A2 = wpa[2], A3 = wpa[3];
    float4 B0 = wpb[0], B1 = wpb[1], B2 = wpb[2], B3 = wpb[3];
    float4 C0 = wpc[0], C1 = wpc[1], C2 = wpc[2], C3 = wpc[3];
    float4 D0 = wpd[0], D1 = wpd[1], D2 = wpd[2], D3 = wpd[3];

    const float* pb = pre + (long)b * 2048 * 256 + j * 4;   // + t*256
    float4 pc0, pc1, pc2, pc3, pn0, pn1, pn2, pn3;
    {   // chunk 0: lane kq holds steps kq*4 .. kq*4+3
        pc0 = *(const float4*)(pb + (kq * 4 + 0) * 256);
        pc1 = *(const float4*)(pb + (kq * 4 + 1) * 256);
        pc2 = *(const float4*)(pb + (kq * 4 + 2) * 256);
        pc3 = *(const float4*)(pb + (kq * 4 + 3) * 256);
    }

    if (tid < 64) hbuf[1][tid] = 0.0f;   // read parity at k=0 is (0+1)&1 = 1
    float cst = 0.0f;
    __syncthreads();

#define STEP(k, pcr) { \
        const float4* hp_ = (const float4*)&hbuf[((k) + 1) & 1][kq * 16]; \
        float4 h0_ = hp_[0], h1_ = hp_[1], h2_ = hp_[2], h3_ = hp_[3]; \
        float p0 = dot4(A3, h3_, dot4(A2, h2_, dot4(A1, h1_, dot4(A0, h0_, 0.f)))); \
        float p1 = dot4(B3, h3_, dot4(B2, h2_, dot4(B1, h1_, dot4(B0, h0_, 0.f)))); \
        float p2 = dot4(C3, h3_, dot4(C2, h2_, dot4(C1, h1_, dot4(C0, h0_, 0.f)))); \
        float p3 = dot4(D3, h3_, dot4(D2, h2_, dot4(D1, h1_, dot4(D0, h0_, 0.f)))); \
        p0 += DPPF(p0, 0xB1); p1 += DPPF(p1, 0xB1); p2 += DPPF(p2, 0xB1); p3 += DPPF(p3, 0xB1); \
        p0 += DPPF(p0, 0x4E); p1 += DPPF(p1, 0x4E); p2 += DPPF(p2, 0x4E); p3 += DPPF(p3, 0x4E); \
        float px = DPPF(pcr.x, 0x55 * ((k) >> 2)); \
        float py = DPPF(pcr.y, 0x55 * ((k) >> 2)); \
        float pz = DPPF(pcr.z, 0x55 * ((k) >> 2)); \
        float pw = DPPF(pcr.w, 0x55 * ((k) >> 2)); \
        float gi = 1.0f - fast_rcp(__expf(p0 + px) + 1.0f); \
        float gf = 1.0f - fast_rcp(__expf(p1 + py) + 1.0f); \
        float gg = 1.0f - 2.0f * fast_rcp(__expf(2.0f * (p2 + pz)) + 1.0f); \
        float go = 1.0f - fast_rcp(__expf(p3 + pw) + 1.0f); \
        cst = fmaf(gf, cst, gi * gg); \
        float h_ = go * tanhfast(cst); \
        if (kq == 0) { hbuf[(k) & 1][j] = h_; rw[(k)][j] = h_; } \
        __syncthreads(); \
    }

    for (int c = 0; c < 128; ++c) {
        if (c > 0) {   // flush previous chunk's h to global (drains at STEP(0)'s barrier)
            float4 v = ((const float4*)ring[(c - 1) & 1])[tid];
            *(float4*)&hout[((long)b * 2048 + (c - 1) * 16) * 64 + tid * 4] = v;
        }
        if (c < 127) {   // prefetch next chunk's pre-activations
            const float* pn = pb + ((c + 1) * 16 + kq * 4) * 256;
            pn0 = *(const float4*)(pn + 0 * 256);
            pn1 = *(const float4*)(pn + 1 * 256);
            pn2 = *(const float4*)(pn + 2 * 256);
            pn3 = *(const float4*)(pn + 3 * 256);
        }
        float (* __restrict__ rw)[64] = ring[c & 1];
        STEP(0,  pc0) STEP(1,  pc1) STEP(2,  pc2) STEP(3,  pc3)
        STEP(4,  pc0) STEP(5,  pc1) STEP(6,  pc2) STEP(7,  pc3)
        STEP(8,  pc0) STEP(9,  pc1) STEP(10, pc2) STEP(11, pc3)
        STEP(12, pc0) STEP(13, pc1) STEP(14, pc2) STEP(15, pc3)
        pc0 = pn0; pc1 = pn1; pc2 = pn2; pc3 = pn3;
    }
#undef STEP
    {   // final flush (chunk 127, parity 1)
        float4 v = ((const float4*)ring[1])[tid];
        *(float4*)&hout[((long)b * 2048 + 127 * 16) * 64 + tid * 4] = v;
    }
}

// ---------------- FC head ----------------
__global__ __launch_bounds__(256) void fc_kernel(
    const float* __restrict__ h2o,
    const float* __restrict__ fc1w, const float* __restrict__ fc1b,
    const float* __restrict__ fc2w, const float* __restrict__ fc2b,
    float* __restrict__ out)
{
    int r = blockIdx.x * 256 + threadIdx.x;
    float h[64];
    const float4* hp = (const float4*)(h2o + (long)r * 64);
    #pragma unroll
    for (int i = 0; i < 16; ++i) {
        float4 v = hp[i];
        h[4 * i] = v.x; h[4 * i + 1] = v.y; h[4 * i + 2] = v.z; h[4 * i + 3] = v.w;
    }
    float l0 = fc2b[0], l1 = fc2b[1];
    #pragma unroll 4
    for (int j = 0; j < 32; ++j) {
        float z = fc1b[j];
        #pragma unroll
        for (int k = 0; k < 64; ++k) z = fmaf(h[k], fc1w[j * 64 + k], z);
        z = fmaxf(z, 0.0f);
        l0 = fmaf(z, fc2w[j], l0);
        l1 = fmaf(z, fc2w[32 + j], l1);
    }
    out[r * 2] = l0;
    out[r * 2 + 1] = l1;
}

extern "C" void kernel_launch(void* const* d_in, const int* in_sizes, int n_in,
                              void* d_out, int out_size, void* d_ws, size_t ws_size,
                              hipStream_t stream) {
    const float* x    = (const float*)d_in[0];
    const float* w1   = (const float*)d_in[1];
    const float* b1   = (const float*)d_in[2];
    const float* g1   = (const float*)d_in[3];
    const float* be1  = (const float*)d_in[4];
    const float* m1   = (const float*)d_in[5];
    const float* v1   = (const float*)d_in[6];
    const float* w2   = (const float*)d_in[7];
    const float* b2   = (const float*)d_in[8];
    const float* g2   = (const float*)d_in[9];
    const float* be2  = (const float*)d_in[10];
    const float* m2   = (const float*)d_in[11];
    const float* v2   = (const float*)d_in[12];
    const float* w3   = (const float*)d_in[13];
    const float* b3   = (const float*)d_in[14];
    const float* g3   = (const float*)d_in[15];
    const float* be3  = (const float*)d_in[16];
    const float* m3   = (const float*)d_in[17];
    const float* v3   = (const float*)d_in[18];
    const float* wih0 = (const float*)d_in[19];
    const float* whh0 = (const float*)d_in[20];
    const float* bih0 = (const float*)d_in[21];
    const float* bhh0 = (const float*)d_in[22];
    const float* wih1 = (const float*)d_in[23];
    const float* whh1 = (const float*)d_in[24];
    const float* bih1 = (const float*)d_in[25];
    const float* bhh1 = (const float*)d_in[26];
    const float* fc1w = (const float*)d_in[27];
    const float* fc1b = (const float*)d_in[28];
    const float* fc2w = (const float*)d_in[29];
    const float* fc2b = (const float*)d_in[30];
    float* out = (float*)d_out;

    float* ws    = (float*)d_ws;
    float* feats = ws;                            // 524288 floats
    float* h2o   = feats + 32768 * 16;            // 2097152 floats
    float* w2t2  = h2o + 32768 * 64;              // 16384 floats
    float* w3p4f = w2t2 + 16384;                  // 2048 floats
    float* w3p1  = w3p4f + 2048;                  // 512 floats
    float* h1o   = w3p1 + 512;                    // 2097152 floats
    float* preb  = h1o + 32768 * 64;              // 8388608 floats (32 MB, reused by both phases)

    hipLaunchKernelGGL(pack_kernel, dim3(66), dim3(256), 0, stream,
                       w2, w3, w2t2, (float4*)w3p4f, w3p1);
    hipLaunchKernelGGL(cnn_kernel, dim3(32768), dim3(256), 0, stream,
                       x, w1, b1, g1, be1, m1, v1, b2, g2, be2, m2, v2,
                       b3, g3, be3, m3, v3, w2t2, (const float4*)w3p4f, w3p1, feats);
    hipLaunchKernelGGL((pre_gemm_kernel<16>), dim3(2048), dim3(256), 0, stream,
                       feats, wih0, bih0, bhh0, preb);
    hipLaunchKernelGGL(lstm_rec_kernel, dim3(16), dim3(256), 0, stream,
                       preb, whh0, h1o);
    hipLaunchKernelGGL((pre_gemm_kernel<64>), dim3(2048), dim3(256), 0, stream,
                       h1o, wih1, bih1, bhh1, preb);
    hipLaunchKernelGGL(lstm_rec_kernel, dim3(16), dim3(256), 0, stream,
                       preb, whh1, h2o);
    hipLaunchKernelGGL(fc_kernel, dim3(128), dim3(256), 0, stream,
                       h2o, fc1w, fc1b, fc2w, fc2b, out);
}

// Round 8
// 1339.148 us; speedup vs baseline: 2.9856x; 2.0605x over previous
//
#include <hip/hip_runtime.h>

#define EPSV 1e-5f
#define SCOPE_AGENT __HIP_MEMORY_SCOPE_AGENT

__device__ __forceinline__ float fast_rcp(float x) { return __builtin_amdgcn_rcpf(x); }
__device__ __forceinline__ float tanhfast(float x) {
    float e = __expf(2.0f * x);
    return 1.0f - 2.0f * fast_rcp(e + 1.0f);
}
__device__ __forceinline__ float dot4(const float4 w, const float4 v, float a) {
    a = fmaf(w.x, v.x, a);
    a = fmaf(w.y, v.y, a);
    a = fmaf(w.z, v.z, a);
    a = fmaf(w.w, v.w, a);
    return a;
}
#define DPPF(v, ctrl) __int_as_float(__builtin_amdgcn_mov_dpp(__float_as_int(v), (ctrl), 0xF, 0xF, false))

typedef unsigned long long ull;

// LDS overlays. Rec slices padded to 20 floats (banks {0-3,20-23,8-11,28-31}) -> conflict-free b128.
struct CnnS {
    float winh[64];
    float w1t[576];
    float a1[64 * 84 + 32];
    float a2[32 * 56 + 16];
    float s1[64], t1[64], s2[32], t2[32], s3[16], t3[16];
    float psum[256];
};
struct RecS {
    float hbuf[2][80];     // slice kq at [par][kq*20 + r], r<16
    float ring[16][64];    // h output staging per chunk
    float xst[16][80];     // L0: feats row [k][0..15]; L1: h1 slices [k][kq*20+r]
};

// ------- pack: w2 -> w2t2; w3 -> w3p4/w3p1; zero cnt0[2048]+flag1[2048] -------
__global__ void pack_kernel(const float* __restrict__ w2, const float* __restrict__ w3,
                            float* __restrict__ w2t2, float4* __restrict__ w3p4,
                            float* __restrict__ w3p1, int* __restrict__ sync_ints) {
    int j = blockIdx.x * 256 + threadIdx.x;
    if (j < 16384) {
        int i = j >> 8;
        int o = (j >> 3) & 31;
        int k = j & 7;
        w2t2[j] = (k < 7) ? w2[o * 448 + i * 7 + k] : 0.0f;
    } else if (j < 16896) {
        int e = j - 16384;
        int i = e >> 4, o = e & 15;
        int base = o * 160 + i * 5;
        w3p4[e] = make_float4(w3[base], w3[base + 1], w3[base + 2], w3[base + 3]);
        w3p1[e] = w3[base + 4];
    } else if (j < 16896 + 4096) {
        sync_ints[j - 16896] = 0;   // d_ws re-poisoned 0xAA every launch -> must re-zero
    }
}

// ================= layer-0 recurrence body (one block per batch b) =================
__device__ __forceinline__ void rec0_body(char* smemraw, int b,
    const float* __restrict__ feats,
    const float* __restrict__ wih, const float* __restrict__ whh,
    const float* __restrict__ bih, const float* __restrict__ bhh,
    float* __restrict__ hout, int* __restrict__ cnt0, int* __restrict__ flag1)
{
    RecS* s = (RecS*)smemraw;
    const int tid = threadIdx.x;
    const int j = tid >> 2, kq = tid & 3;

    const float4* pa = (const float4*)(whh + (0 * 64 + j) * 64 + kq * 16);
    const float4* pb = (const float4*)(whh + (1 * 64 + j) * 64 + kq * 16);
    const float4* pc_ = (const float4*)(whh + (2 * 64 + j) * 64 + kq * 16);
    const float4* pd = (const float4*)(whh + (3 * 64 + j) * 64 + kq * 16);
    float4 A0 = pa[0], A1 = pa[1], A2 = pa[2], A3 = pa[3];
    float4 B0 = pb[0], B1 = pb[1], B2 = pb[2], B3 = pb[3];
    float4 C0 = pc_[0], C1 = pc_[1], C2 = pc_[2], C3 = pc_[3];
    float4 D0 = pd[0], D1 = pd[1], D2 = pd[2], D3 = pd[3];
    float4 xw0 = *(const float4*)(wih + (0 * 64 + j) * 16 + kq * 4);
    float4 xw1 = *(const float4*)(wih + (1 * 64 + j) * 16 + kq * 4);
    float4 xw2 = *(const float4*)(wih + (2 * 64 + j) * 16 + kq * 4);
    float4 xw3 = *(const float4*)(wih + (3 * 64 + j) * 16 + kq * 4);
    const float bb0 = bih[j] + bhh[j];
    const float bb1 = bih[64 + j] + bhh[64 + j];
    const float bb2 = bih[128 + j] + bhh[128 + j];
    const float bb3 = bih[192 + j] + bhh[192 + j];

    if (tid < 64) s->hbuf[1][(tid >> 4) * 20 + (tid & 15)] = 0.0f;
    float cst = 0.0f;
    const float* fbase = feats + (long)b * 32768;
    __syncthreads();

#define STEP0(k) { \
        const float4* hp_ = (const float4*)&s->hbuf[((k) + 1) & 1][kq * 20]; \
        float4 h0_ = hp_[0], h1_ = hp_[1], h2_ = hp_[2], h3_ = hp_[3]; \
        float4 xv_ = *(const float4*)&s->xst[(k)][kq * 4]; \
        float p0 = dot4(A3, h3_, dot4(A2, h2_, dot4(A1, h1_, dot4(A0, h0_, dot4(xw0, xv_, 0.f))))); \
        float p1 = dot4(B3, h3_, dot4(B2, h2_, dot4(B1, h1_, dot4(B0, h0_, dot4(xw1, xv_, 0.f))))); \
        float p2 = dot4(C3, h3_, dot4(C2, h2_, dot4(C1, h1_, dot4(C0, h0_, dot4(xw2, xv_, 0.f))))); \
        float p3 = dot4(D3, h3_, dot4(D2, h2_, dot4(D1, h1_, dot4(D0, h0_, dot4(xw3, xv_, 0.f))))); \
        p0 += DPPF(p0, 0xB1); p1 += DPPF(p1, 0xB1); p2 += DPPF(p2, 0xB1); p3 += DPPF(p3, 0xB1); \
        p0 += DPPF(p0, 0x4E); p1 += DPPF(p1, 0x4E); p2 += DPPF(p2, 0x4E); p3 += DPPF(p3, 0x4E); \
        float gi = 1.0f - fast_rcp(__expf(p0 + bb0) + 1.0f); \
        float gf = 1.0f - fast_rcp(__expf(p1 + bb1) + 1.0f); \
        float gg = 1.0f - 2.0f * fast_rcp(__expf(2.0f * (p2 + bb2)) + 1.0f); \
        float go = 1.0f - fast_rcp(__expf(p3 + bb3) + 1.0f); \
        cst = fmaf(gf, cst, gi * gg); \
        float h_ = go * tanhfast(cst); \
        if (kq == 0) { s->hbuf[(k) & 1][(j >> 4) * 20 + (j & 15)] = h_; s->ring[(k)][j] = h_; } \
        __syncthreads(); \
    }

    for (int c = 0; c < 128; ++c) {
        if (tid == 0) {
            while (__hip_atomic_load(&cnt0[b * 128 + c], __ATOMIC_RELAXED, SCOPE_AGENT) < 16)
                __builtin_amdgcn_s_sleep(2);
        }
        __syncthreads();
        s->xst[tid >> 4][tid & 15] =
            __hip_atomic_load(fbase + c * 256 + tid, __ATOMIC_RELAXED, SCOPE_AGENT);
        __syncthreads();
        STEP0(0)  STEP0(1)  STEP0(2)  STEP0(3)
        STEP0(4)  STEP0(5)  STEP0(6)  STEP0(7)
        STEP0(8)  STEP0(9)  STEP0(10) STEP0(11)
        STEP0(12) STEP0(13) STEP0(14) STEP0(15)
        {   // flush h1 chunk via coherent 8B stores, then flag (after vmcnt drain)
            ull* dst = (ull*)(hout + ((long)b * 2048 + c * 16) * 64);
            ull v0 = ((const ull*)s->ring)[tid];
            ull v1 = ((const ull*)s->ring)[tid + 256];
            __hip_atomic_store(dst + tid, v0, __ATOMIC_RELAXED, SCOPE_AGENT);
            __hip_atomic_store(dst + tid + 256, v1, __ATOMIC_RELAXED, SCOPE_AGENT);
            __syncthreads();   // drains vmcnt(0): stores at coherent point before flag
            if (tid == 0)
                __hip_atomic_store(&flag1[b * 128 + c], 1, __ATOMIC_RELAXED, SCOPE_AGENT);
        }
    }
#undef STEP0
}

// ================= layer-1 recurrence body (wih.h1 fused into the step) =================
__device__ __forceinline__ void rec1_body(char* smemraw, int b,
    const float* __restrict__ h1o,
    const float* __restrict__ wih, const float* __restrict__ whh,
    const float* __restrict__ bih, const float* __restrict__ bhh,
    float* __restrict__ hout, int* __restrict__ flag1)
{
    RecS* s = (RecS*)smemraw;
    const int tid = threadIdx.x;
    const int j = tid >> 2, kq = tid & 3;

    const float4* pa = (const float4*)(whh + (0 * 64 + j) * 64 + kq * 16);
    const float4* pb = (const float4*)(whh + (1 * 64 + j) * 64 + kq * 16);
    const float4* pc_ = (const float4*)(whh + (2 * 64 + j) * 64 + kq * 16);
    const float4* pd = (const float4*)(whh + (3 * 64 + j) * 64 + kq * 16);
    float4 A0 = pa[0], A1 = pa[1], A2 = pa[2], A3 = pa[3];
    float4 B0 = pb[0], B1 = pb[1], B2 = pb[2], B3 = pb[3];
    float4 C0 = pc_[0], C1 = pc_[1], C2 = pc_[2], C3 = pc_[3];
    float4 D0 = pd[0], D1 = pd[1], D2 = pd[2], D3 = pd[3];
    const float4* qa = (const float4*)(wih + (0 * 64 + j) * 64 + kq * 16);
    const float4* qb = (const float4*)(wih + (1 * 64 + j) * 64 + kq * 16);
    const float4* qc = (const float4*)(wih + (2 * 64 + j) * 64 + kq * 16);
    const float4* qd = (const float4*)(wih + (3 * 64 + j) * 64 + kq * 16);
    float4 XA0 = qa[0], XA1 = qa[1], XA2 = qa[2], XA3 = qa[3];
    float4 XB0 = qb[0], XB1 = qb[1], XB2 = qb[2], XB3 = qb[3];
    float4 XC0 = qc[0], XC1 = qc[1], XC2 = qc[2], XC3 = qc[3];
    float4 XD0 = qd[0], XD1 = qd[1], XD2 = qd[2], XD3 = qd[3];
    const float bb0 = bih[j] + bhh[j];
    const float bb1 = bih[64 + j] + bhh[64 + j];
    const float bb2 = bih[128 + j] + bhh[128 + j];
    const float bb3 = bih[192 + j] + bhh[192 + j];

    if (tid < 64) s->hbuf[1][(tid >> 4) * 20 + (tid & 15)] = 0.0f;
    float cst = 0.0f;
    __syncthreads();

#define STEP1(k) { \
        const float4* hp_ = (const float4*)&s->hbuf[((k) + 1) & 1][kq * 20]; \
        float4 h0_ = hp_[0], h1_ = hp_[1], h2_ = hp_[2], h3_ = hp_[3]; \
        const float4* xp_ = (const float4*)&s->xst[(k)][kq * 20]; \
        float4 x0_ = xp_[0], x1_ = xp_[1], x2_ = xp_[2], x3_ = xp_[3]; \
        float p0 = dot4(A3, h3_, dot4(A2, h2_, dot4(A1, h1_, dot4(A0, h0_, \
                   dot4(XA3, x3_, dot4(XA2, x2_, dot4(XA1, x1_, dot4(XA0, x0_, 0.f)))))))); \
        float p1 = dot4(B3, h3_, dot4(B2, h2_, dot4(B1, h1_, dot4(B0, h0_, \
                   dot4(XB3, x3_, dot4(XB2, x2_, dot4(XB1, x1_, dot4(XB0, x0_, 0.f)))))))); \
        float p2 = dot4(C3, h3_, dot4(C2, h2_, dot4(C1, h1_, dot4(C0, h0_, \
                   dot4(XC3, x3_, dot4(XC2, x2_, dot4(XC1, x1_, dot4(XC0, x0_, 0.f)))))))); \
        float p3 = dot4(D3, h3_, dot4(D2, h2_, dot4(D1, h1_, dot4(D0, h0_, \
                   dot4(XD3, x3_, dot4(XD2, x2_, dot4(XD1, x1_, dot4(XD0, x0_, 0.f)))))))); \
        p0 += DPPF(p0, 0xB1); p1 += DPPF(p1, 0xB1); p2 += DPPF(p2, 0xB1); p3 += DPPF(p3, 0xB1); \
        p0 += DPPF(p0, 0x4E); p1 += DPPF(p1, 0x4E); p2 += DPPF(p2, 0x4E); p3 += DPPF(p3, 0x4E); \
        float gi = 1.0f - fast_rcp(__expf(p0 + bb0) + 1.0f); \
        float gf = 1.0f - fast_rcp(__expf(p1 + bb1) + 1.0f); \
        float gg = 1.0f - 2.0f * fast_rcp(__expf(2.0f * (p2 + bb2)) + 1.0f); \
        float go = 1.0f - fast_rcp(__expf(p3 + bb3) + 1.0f); \
        cst = fmaf(gf, cst, gi * gg); \
        float h_ = go * tanhfast(cst); \
        if (kq == 0) { s->hbuf[(k) & 1][(j >> 4) * 20 + (j & 15)] = h_; s->ring[(k)][j] = h_; } \
        __syncthreads(); \
    }

    for (int c = 0; c < 128; ++c) {
        if (tid == 0) {
            while (__hip_atomic_load(&flag1[b * 128 + c], __ATOMIC_RELAXED, SCOPE_AGENT) < 1)
                __builtin_amdgcn_s_sleep(2);
        }
        __syncthreads();
        {   // stage h1 chunk (coherent 8B loads) into padded slices
            const ull* src = (const ull*)(h1o + ((long)b * 2048 + c * 16) * 64);
            ull v0 = __hip_atomic_load(src + tid, __ATOMIC_RELAXED, SCOPE_AGENT);
            ull v1 = __hip_atomic_load(src + tid + 256, __ATOMIC_RELAXED, SCOPE_AGENT);
            int u0 = tid, u1 = tid + 256;
            int k0 = u0 >> 5, p0i = (u0 & 31) * 2;
            int k1 = u1 >> 5, p1i = (u1 & 31) * 2;
            *(ull*)&s->xst[k0][(p0i >> 4) * 20 + (p0i & 15)] = v0;
            *(ull*)&s->xst[k1][(p1i >> 4) * 20 + (p1i & 15)] = v1;
        }
        __syncthreads();
        STEP1(0)  STEP1(1)  STEP1(2)  STEP1(3)
        STEP1(4)  STEP1(5)  STEP1(6)  STEP1(7)
        STEP1(8)  STEP1(9)  STEP1(10) STEP1(11)
        STEP1(12) STEP1(13) STEP1(14) STEP1(15)
        {   // flush h2 chunk (plain stores; consumer is the next kernel)
            float4* dst = (float4*)(hout + ((long)b * 2048 + c * 16) * 64);
            dst[tid] = ((const float4*)s->ring)[tid];
        }
    }
#undef STEP1
}

// ================= fused kernel: blocks 0-15 lstm0, 16-31 lstm1, 32+ CNN (t-major) =================
__global__ __launch_bounds__(256, 2) void fused_kernel(
    const float* __restrict__ x,
    const float* __restrict__ w1, const float* __restrict__ b1,
    const float* __restrict__ g1, const float* __restrict__ be1,
    const float* __restrict__ m1, const float* __restrict__ v1,
    const float* __restrict__ b2,
    const float* __restrict__ g2, const float* __restrict__ be2,
    const float* __restrict__ m2, const float* __restrict__ v2,
    const float* __restrict__ b3,
    const float* __restrict__ g3, const float* __restrict__ be3,
    const float* __restrict__ m3, const float* __restrict__ v3,
    const float* __restrict__ w2t2,
    const float4* __restrict__ w3p4, const float* __restrict__ w3p1,
    const float* __restrict__ wih0, const float* __restrict__ whh0,
    const float* __restrict__ bih0, const float* __restrict__ bhh0,
    const float* __restrict__ wih1, const float* __restrict__ whh1,
    const float* __restrict__ bih1, const float* __restrict__ bhh1,
    float* __restrict__ feats, float* __restrict__ h1o, float* __restrict__ h2o,
    int* __restrict__ cnt0, int* __restrict__ flag1)
{
    __shared__ __align__(16) char smem[sizeof(CnnS)];
    static_assert(sizeof(RecS) <= sizeof(CnnS), "RecS must fit in CnnS");

    if (blockIdx.x < 16) { rec0_body(smem, blockIdx.x, feats, wih0, whh0, bih0, bhh0, h1o, cnt0, flag1); return; }
    if (blockIdx.x < 32) { rec1_body(smem, blockIdx.x - 16, h1o, wih1, whh1, bih1, bhh1, h2o, flag1); return; }

    // ---------------- CNN role ----------------
    CnnS* cs = (CnnS*)smem;
    const int tid = threadIdx.x;
    const int w = blockIdx.x - 32;
    const int b = w & 15;          // t-major: early t for all batches first
    const int t = w >> 4;

    for (int idx = tid; idx < 576; idx += 256) {
        int o = idx / 9, k = idx % 9;
        cs->w1t[k * 64 + o] = w1[idx];
    }
    if (tid < 64) {
        float s = g1[tid] * rsqrtf(v1[tid] + EPSV);
        cs->s1[tid] = s;
        cs->t1[tid] = (b1[tid] - m1[tid]) * s + be1[tid];
    } else if (tid < 96) {
        int o = tid - 64;
        float s = g2[o] * rsqrtf(v2[o] + EPSV);
        cs->s2[o] = s;
        cs->t2[o] = (b2[o] - m2[o]) * s + be2[o];
    } else if (tid < 112) {
        int o = tid - 96;
        float s = g3[o] * rsqrtf(v3[o] + EPSV);
        cs->s3[o] = s;
        cs->t3[o] = (b3[o] - m3[o]) * s + be3[o];
    }
    if (tid < 64) {
        cs->winh[tid] = 0.0f;
        float* r = &cs->a1[tid * 84];
        r[0] = 0.f; r[1] = 0.f; r[2] = 0.f;
        r[77] = 0.f; r[78] = 0.f; r[79] = 0.f;
    }
    if (tid < 32) {
        float* r = &cs->a2[tid * 56];
        r[0] = 0.f; r[1] = 0.f;
        r[52] = 0.f; r[53] = 0.f; r[54] = 0.f; r[55] = 0.f;
    }
    __syncthreads();
    if (tid < 50) {
        int gi = t + tid - 49;
        cs->winh[4 + tid] = (gi >= 0) ? x[b * 2048 + gi] : 0.0f;
    }
    __syncthreads();

    {   // conv1
        int o = tid >> 2, pg = tid & 3;
        int p0 = pg * 13;
        float wv[9];
        #pragma unroll
        for (int k = 0; k < 9; ++k) wv[k] = cs->w1t[k * 64 + o];
        float sc = cs->s1[o], tc = cs->t1[o];
        #pragma unroll
        for (int q = 0; q < 13; ++q) {
            int p = p0 + q;
            if (p < 50) {
                float acc = 0.0f;
                #pragma unroll
                for (int k = 0; k < 9; ++k) acc = fmaf(wv[k], cs->winh[p + k], acc);
                int pi = p + 3;
                int slot = pi + ((pi >> 3) << 2);
                cs->a1[o * 84 + slot] = fmaxf(acc * sc + tc, 0.0f);
            }
        }
    }
    __syncthreads();

    {   // conv2
        int o = tid >> 3, pg = tid & 7;
        float acc[8];
        #pragma unroll
        for (int q = 0; q < 8; ++q) acc[q] = 0.0f;
        for (int i = 0; i < 64; ++i) {
            const float* rowp = &cs->a1[i * 84 + 12 * pg];
            float4 A0 = *(const float4*)&rowp[0];
            float4 A1 = *(const float4*)&rowp[4];
            float4 A2 = *(const float4*)&rowp[12];
            float2 A3 = *(const float2*)&rowp[16];
            const float4* wp = (const float4*)&w2t2[(i * 32 + o) * 8];
            float4 Wa = wp[0], Wb = wp[1];
            float av[14] = {A0.x, A0.y, A0.z, A0.w, A1.x, A1.y, A1.z, A1.w,
                            A2.x, A2.y, A2.z, A2.w, A3.x, A3.y};
            float wk[7] = {Wa.x, Wa.y, Wa.z, Wa.w, Wb.x, Wb.y, Wb.z};
            #pragma unroll
            for (int k = 0; k < 7; ++k) {
                #pragma unroll
                for (int q = 0; q < 8; ++q) acc[q] = fmaf(wk[k], av[q + k], acc[q]);
            }
        }
        float sc = cs->s2[o], tc = cs->t2[o];
        float r[8];
        #pragma unroll
        for (int q = 0; q < 8; ++q) r[q] = fmaxf(acc[q] * sc + tc, 0.0f);
        float* row = &cs->a2[o * 56 + 8 * pg];
        if (pg < 6) {
            *(float2*)&row[2] = make_float2(r[0], r[1]);
            *(float4*)&row[4] = make_float4(r[2], r[3], r[4], r[5]);
            *(float2*)&row[8] = make_float2(r[6], r[7]);
        } else if (pg == 6) {
            *(float2*)&row[2] = make_float2(r[0], r[1]);
        }
    }
    __syncthreads();

    {   // conv3 + mean partials
        int o = tid & 15, pg = tid >> 4;
        float acc[4];
        #pragma unroll
        for (int q = 0; q < 4; ++q) acc[q] = 0.0f;
        for (int i = 0; i < 32; ++i) {
            float4 wa = w3p4[i * 16 + o];
            float w4 = w3p1[i * 16 + o];
            const float4* ap = (const float4*)&cs->a2[i * 56 + 4 * pg];
            float4 Aa = ap[0], Ab = ap[1];
            float av[8] = {Aa.x, Aa.y, Aa.z, Aa.w, Ab.x, Ab.y, Ab.z, Ab.w};
            #pragma unroll
            for (int q = 0; q < 4; ++q) {
                acc[q] = fmaf(wa.x, av[q], acc[q]);
                acc[q] = fmaf(wa.y, av[q + 1], acc[q]);
                acc[q] = fmaf(wa.z, av[q + 2], acc[q]);
                acc[q] = fmaf(wa.w, av[q + 3], acc[q]);
                acc[q] = fmaf(w4,   av[q + 4], acc[q]);
            }
        }
        float sc = cs->s3[o], tc = cs->t3[o];
        float ps = 0.0f;
        #pragma unroll
        for (int q = 0; q < 4; ++q) {
            int p = 4 * pg + q;
            if (p < 50) ps += fmaxf(acc[q] * sc + tc, 0.0f);
        }
        cs->psum[pg * 16 + o] = ps;
    }
    __syncthreads();

    if (tid < 16) {
        float s = 0.0f;
        #pragma unroll
        for (int pg = 0; pg < 16; ++pg) s += cs->psum[pg * 16 + tid];
        // coherent store: visible at L3 before the counter increment below
        __hip_atomic_store(&feats[((long)b * 2048 + t) * 16 + tid], s * (1.0f / 50.0f),
                           __ATOMIC_RELAXED, SCOPE_AGENT);
    }
    __syncthreads();   // drains vmcnt(0): feats stores complete before counter bump
    if (tid == 0)
        __hip_atomic_fetch_add(&cnt0[b * 128 + (t >> 4)], 1, __ATOMIC_RELAXED, SCOPE_AGENT);
}

// ---------------- FC head ----------------
__global__ __launch_bounds__(256) void fc_kernel(
    const float* __restrict__ h2o,
    const float* __restrict__ fc1w, const float* __restrict__ fc1b,
    const float* __restrict__ fc2w, const float* __restrict__ fc2b,
    float* __restrict__ out)
{
    int r = blockIdx.x * 256 + threadIdx.x;
    float h[64];
    const float4* hp = (const float4*)(h2o + (long)r * 64);
    #pragma unroll
    for (int i = 0; i < 16; ++i) {
        float4 v = hp[i];
        h[4 * i] = v.x; h[4 * i + 1] = v.y; h[4 * i + 2] = v.z; h[4 * i + 3] = v.w;
    }
    float l0 = fc2b[0], l1 = fc2b[1];
    #pragma unroll 4
    for (int j = 0; j < 32; ++j) {
        float z = fc1b[j];
        #pragma unroll
        for (int k = 0; k < 64; ++k) z = fmaf(h[k], fc1w[j * 64 + k], z);
        z = fmaxf(z, 0.0f);
        l0 = fmaf(z, fc2w[j], l0);
        l1 = fmaf(z, fc2w[32 + j], l1);
    }
    out[r * 2] = l0;
    out[r * 2 + 1] = l1;
}

extern "C" void kernel_launch(void* const* d_in, const int* in_sizes, int n_in,
                              void* d_out, int out_size, void* d_ws, size_t ws_size,
                              hipStream_t stream) {
    const float* x    = (const float*)d_in[0];
    const float* w1   = (const float*)d_in[1];
    const float* b1   = (const float*)d_in[2];
    const float* g1   = (const float*)d_in[3];
    const float* be1  = (const float*)d_in[4];
    const float* m1   = (const float*)d_in[5];
    const float* v1   = (const float*)d_in[6];
    const float* w2   = (const float*)d_in[7];
    const float* b2   = (const float*)d_in[8];
    const float* g2   = (const float*)d_in[9];
    const float* be2  = (const float*)d_in[10];
    const float* m2   = (const float*)d_in[11];
    const float* v2   = (const float*)d_in[12];
    const float* w3   = (const float*)d_in[13];
    const float* b3   = (const float*)d_in[14];
    const float* g3   = (const float*)d_in[15];
    const float* be3  = (const float*)d_in[16];
    const float* m3   = (const float*)d_in[17];
    const float* v3   = (const float*)d_in[18];
    const float* wih0 = (const float*)d_in[19];
    const float* whh0 = (const float*)d_in[20];
    const float* bih0 = (const float*)d_in[21];
    const float* bhh0 = (const float*)d_in[22];
    const float* wih1 = (const float*)d_in[23];
    const float* whh1 = (const float*)d_in[24];
    const float* bih1 = (const float*)d_in[25];
    const float* bhh1 = (const float*)d_in[26];
    const float* fc1w = (const float*)d_in[27];
    const float* fc1b = (const float*)d_in[28];
    const float* fc2w = (const float*)d_in[29];
    const float* fc2b = (const float*)d_in[30];
    float* out = (float*)d_out;

    float* ws    = (float*)d_ws;
    float* feats = ws;                            // 524288 floats
    float* h2o   = feats + 32768 * 16;            // 2097152 floats
    float* w2t2  = h2o + 32768 * 64;              // 16384 floats
    float* w3p4f = w2t2 + 16384;                  // 2048 floats
    float* w3p1  = w3p4f + 2048;                  // 512 floats
    float* h1o   = w3p1 + 512;                    // 2097152 floats
    int*   cnt0  = (int*)(h1o + 32768 * 64);      // 2048 ints
    int*   flag1 = cnt0 + 2048;                   // 2048 ints

    hipLaunchKernelGGL(pack_kernel, dim3(82), dim3(256), 0, stream,
                       w2, w3, w2t2, (float4*)w3p4f, w3p1, cnt0);
    hipLaunchKernelGGL(fused_kernel, dim3(32 + 32768), dim3(256), 0, stream,
                       x, w1, b1, g1, be1, m1, v1, b2, g2, be2, m2, v2,
                       b3, g3, be3, m3, v3, w2t2, (const float4*)w3p4f, w3p1,
                       wih0, whh0, bih0, bhh0, wih1, whh1, bih1, bhh1,
                       feats, h1o, h2o, cnt0, flag1);
    hipLaunchKernelGGL(fc_kernel, dim3(128), dim3(256), 0, stream,
                       h2o, fc1w, fc1b, fc2w, fc2b, out);
}

// Round 9
// 1197.589 us; speedup vs baseline: 3.3386x; 1.1182x over previous
//
#include <hip/hip_runtime.h>

#define EPSV 1e-5f
#define SCOPE_AGENT __HIP_MEMORY_SCOPE_AGENT

__device__ __forceinline__ float fast_rcp(float x) { return __builtin_amdgcn_rcpf(x); }
__device__ __forceinline__ float tanhfast(float x) {
    float e = __expf(2.0f * x);
    return 1.0f - 2.0f * fast_rcp(e + 1.0f);
}
__device__ __forceinline__ float dot4(const float4 w, const float4 v, float a) {
    a = fmaf(w.x, v.x, a);
    a = fmaf(w.y, v.y, a);
    a = fmaf(w.z, v.z, a);
    a = fmaf(w.w, v.w, a);
    return a;
}
#define DPPF(v, ctrl) __int_as_float(__builtin_amdgcn_mov_dpp(__float_as_int(v), (ctrl), 0xF, 0xF, false))

typedef unsigned long long ull;

// ---- LDS overlays ----
struct RecS {
    float hbuf[2][80];
    float ring[16][64];
    float xst[16][80];
};
struct EdgeS {
    float A1[64 * 40];     // per-o rows: [0..2]=0, [3..16]=a1L(p0..13), [20..33]=a1R(rr0..13), [34..36]=0
    float A2[32 * 32];     // rows: [0,1]=0, [2..12]=a2L(e0..10), [16..26]=a2R(qr0..10), [27,28]=0
    float xeL[24], xeR[24];
    float s1[64], t1[64], s2[32], t2[32], s3[16], t3[16];
    float psumE[288];      // 18 pos x 16 o
    float pi[512];         // 32 dv x 16 o interior a3f
};

// ------- pack: w2 -> w2t2[(i*32+o)*8+k]; w3 -> w3p4/w3p1[(i*16+o)]; zero sync ints -------
__global__ void pack_kernel(const float* __restrict__ w2, const float* __restrict__ w3,
                            float* __restrict__ w2t2, float4* __restrict__ w3p4,
                            float* __restrict__ w3p1, int* __restrict__ sync_ints) {
    int j = blockIdx.x * 256 + threadIdx.x;
    if (j < 16384) {
        int i = j >> 8;
        int o = (j >> 3) & 31;
        int k = j & 7;
        w2t2[j] = (k < 7) ? w2[o * 448 + i * 7 + k] : 0.0f;
    } else if (j < 16896) {
        int e = j - 16384;
        int i = e >> 4, o = e & 15;
        int base = o * 160 + i * 5;
        w3p4[e] = make_float4(w3[base], w3[base + 1], w3[base + 2], w3[base + 3]);
        w3p1[e] = w3[base + 4];
    } else if (j < 16896 + 4096) {
        sync_ints[j - 16896] = 0;
    }
}

// ---------------- full-seq conv1: a1f[(b*2089+v1)*64+i], u=v1-45, taps xe(v1-49+k) ----------------
__global__ __launch_bounds__(256) void conv1f_kernel(
    const float* __restrict__ x, const float* __restrict__ w1,
    const float* __restrict__ b1, const float* __restrict__ g1,
    const float* __restrict__ be1, const float* __restrict__ m1,
    const float* __restrict__ vv1, float* __restrict__ a1f)
{
    __shared__ float xs[72];
    const int tid = threadIdx.x;
    const int T = blockIdx.x * 64;
    const int b = blockIdx.y;
    if (tid < 72) {
        int gi = T - 49 + tid;
        xs[tid] = (gi >= 0 && gi < 2048) ? x[b * 2048 + gi] : 0.0f;
    }
    const int i = tid & 63, q = tid >> 6;
    float wv[9];
    #pragma unroll
    for (int k = 0; k < 9; ++k) wv[k] = w1[i * 9 + k];
    float sc = g1[i] * rsqrtf(vv1[i] + EPSV);
    float tc = (b1[i] - m1[i]) * sc + be1[i];
    __syncthreads();
    #pragma unroll
    for (int r = 0; r < 16; ++r) {
        int v1 = T + q * 16 + r;
        if (v1 < 2089) {
            float acc = 0.0f;
            #pragma unroll
            for (int k = 0; k < 9; ++k) acc = fmaf(wv[k], xs[q * 16 + r + k], acc);
            a1f[((long)b * 2089 + v1) * 64 + i] = fmaxf(acc * sc + tc, 0.0f);
        }
    }
}

// ---------------- full-seq conv2: a2f[(b*2083+v2)*32+o], taps a1f[v2+k] ----------------
__global__ __launch_bounds__(256) void conv2f_kernel(
    const float* __restrict__ a1f, const float* __restrict__ w2t2,
    const float* __restrict__ b2, const float* __restrict__ g2,
    const float* __restrict__ be2, const float* __restrict__ m2,
    const float* __restrict__ vv2, float* __restrict__ a2f)
{
    __shared__ __align__(16) float As[64 * 104];
    const int tid = threadIdx.x;
    const int T = blockIdx.x * 64;
    const int b = blockIdx.y;
    for (int idx = tid; idx < 1120; idx += 256) {
        int j = idx >> 4, i4 = (idx & 15) * 4;
        int v1 = T + j; if (v1 > 2088) v1 = 2088;
        float4 f = *(const float4*)&a1f[((long)b * 2089 + v1) * 64 + i4];
        int sj = j + ((j >> 3) << 2);
        As[(i4 + 0) * 104 + sj] = f.x;
        As[(i4 + 1) * 104 + sj] = f.y;
        As[(i4 + 2) * 104 + sj] = f.z;
        As[(i4 + 3) * 104 + sj] = f.w;
    }
    const int o = tid >> 3, pg = tid & 7;
    float sc = g2[o] * rsqrtf(vv2[o] + EPSV);
    float tc = (b2[o] - m2[o]) * sc + be2[o];
    __syncthreads();
    float acc[8];
    #pragma unroll
    for (int q = 0; q < 8; ++q) acc[q] = 0.0f;
    for (int i = 0; i < 64; ++i) {
        const float* rowp = &As[i * 104 + 12 * pg];
        float4 A0 = *(const float4*)&rowp[0];
        float4 A1 = *(const float4*)&rowp[4];
        float4 A2 = *(const float4*)&rowp[12];
        float2 A3 = *(const float2*)&rowp[16];
        const float4* wp = (const float4*)&w2t2[(i * 32 + o) * 8];
        float4 Wa = wp[0], Wb = wp[1];
        float av[14] = {A0.x, A0.y, A0.z, A0.w, A1.x, A1.y, A1.z, A1.w,
                        A2.x, A2.y, A2.z, A2.w, A3.x, A3.y};
        float wk[7] = {Wa.x, Wa.y, Wa.z, Wa.w, Wb.x, Wb.y, Wb.z};
        #pragma unroll
        for (int k = 0; k < 7; ++k) {
            #pragma unroll
            for (int q = 0; q < 8; ++q) acc[q] = fmaf(wk[k], av[q + k], acc[q]);
        }
    }
    #pragma unroll
    for (int q = 0; q < 8; ++q) {
        int v2 = T + pg * 8 + q;
        if (v2 < 2083)
            a2f[((long)b * 2083 + v2) * 32 + o] = fmaxf(acc[q] * sc + tc, 0.0f);
    }
}

// ---------------- full-seq conv3: a3f[(b*2080+v3)*16+o], taps a2f[v3+k] ----------------
__global__ __launch_bounds__(256) void conv3f_kernel(
    const float* __restrict__ a2f,
    const float4* __restrict__ w3p4, const float* __restrict__ w3p1,
    const float* __restrict__ b3, const float* __restrict__ g3,
    const float* __restrict__ be3, const float* __restrict__ m3,
    const float* __restrict__ vv3, float* __restrict__ a3f)
{
    __shared__ __align__(16) float A2s[32 * 200];
    const int tid = threadIdx.x;
    const int T = blockIdx.x * 128;
    const int b = blockIdx.y;
    for (int idx = tid; idx < 1056; idx += 256) {
        int j = idx >> 3, i4 = (idx & 7) * 4;
        int v2 = T + j; if (v2 > 2082) v2 = 2082;
        float4 f = *(const float4*)&a2f[((long)b * 2083 + v2) * 32 + i4];
        int sj = j + ((j >> 3) << 2);
        A2s[(i4 + 0) * 200 + sj] = f.x;
        A2s[(i4 + 1) * 200 + sj] = f.y;
        A2s[(i4 + 2) * 200 + sj] = f.z;
        A2s[(i4 + 3) * 200 + sj] = f.w;
    }
    const int o = tid & 15, pg = tid >> 4;
    float sc = g3[o] * rsqrtf(vv3[o] + EPSV);
    float tc = (b3[o] - m3[o]) * sc + be3[o];
    __syncthreads();
    float acc[8];
    #pragma unroll
    for (int q = 0; q < 8; ++q) acc[q] = 0.0f;
    for (int i = 0; i < 32; ++i) {
        const float* rowp = &A2s[i * 200 + 12 * pg];
        float4 R0 = *(const float4*)&rowp[0];
        float4 R1 = *(const float4*)&rowp[4];
        float4 R2 = *(const float4*)&rowp[12];
        float av[12] = {R0.x, R0.y, R0.z, R0.w, R1.x, R1.y, R1.z, R1.w,
                        R2.x, R2.y, R2.z, R2.w};
        float4 wa = w3p4[i * 16 + o];
        float w4 = w3p1[i * 16 + o];
        #pragma unroll
        for (int q = 0; q < 8; ++q) {
            acc[q] = fmaf(wa.x, av[q], acc[q]);
            acc[q] = fmaf(wa.y, av[q + 1], acc[q]);
            acc[q] = fmaf(wa.z, av[q + 2], acc[q]);
            acc[q] = fmaf(wa.w, av[q + 3], acc[q]);
            acc[q] = fmaf(w4,   av[q + 4], acc[q]);
        }
    }
    #pragma unroll
    for (int q = 0; q < 8; ++q) {
        int v3 = T + pg * 8 + q;
        if (v3 < 2079)
            a3f[((long)b * 2080 + v3) * 16 + o] = fmaxf(acc[q] * sc + tc, 0.0f);
        else if (v3 < 2080)
            a3f[((long)b * 2080 + v3) * 16 + o] = 0.0f;
    }
}

// ================= layer-0 recurrence body (verbatim R8) =================
__device__ __forceinline__ void rec0_body(char* smemraw, int b,
    const float* __restrict__ feats,
    const float* __restrict__ wih, const float* __restrict__ whh,
    const float* __restrict__ bih, const float* __restrict__ bhh,
    float* __restrict__ hout, int* __restrict__ cnt0, int* __restrict__ flag1)
{
    RecS* s = (RecS*)smemraw;
    const int tid = threadIdx.x;
    const int j = tid >> 2, kq = tid & 3;

    const float4* pa = (const float4*)(whh + (0 * 64 + j) * 64 + kq * 16);
    const float4* pb = (const float4*)(whh + (1 * 64 + j) * 64 + kq * 16);
    const float4* pc_ = (const float4*)(whh + (2 * 64 + j) * 64 + kq * 16);
    const float4* pd = (const float4*)(whh + (3 * 64 + j) * 64 + kq * 16);
    float4 A0 = pa[0], A1 = pa[1], A2 = pa[2], A3 = pa[3];
    float4 B0 = pb[0], B1 = pb[1], B2 = pb[2], B3 = pb[3];
    float4 C0 = pc_[0], C1 = pc_[1], C2 = pc_[2], C3 = pc_[3];
    float4 D0 = pd[0], D1 = pd[1], D2 = pd[2], D3 = pd[3];
    float4 xw0 = *(const float4*)(wih + (0 * 64 + j) * 16 + kq * 4);
    float4 xw1 = *(const float4*)(wih + (1 * 64 + j) * 16 + kq * 4);
    float4 xw2 = *(const float4*)(wih + (2 * 64 + j) * 16 + kq * 4);
    float4 xw3 = *(const float4*)(wih + (3 * 64 + j) * 16 + kq * 4);
    const float bb0 = bih[j] + bhh[j];
    const float bb1 = bih[64 + j] + bhh[64 + j];
    const float bb2 = bih[128 + j] + bhh[128 + j];
    const float bb3 = bih[192 + j] + bhh[192 + j];

    if (tid < 64) s->hbuf[1][(tid >> 4) * 20 + (tid & 15)] = 0.0f;
    float cst = 0.0f;
    const float* fbase = feats + (long)b * 32768;
    __syncthreads();

#define STEP0(k) { \
        const float4* hp_ = (const float4*)&s->hbuf[((k) + 1) & 1][kq * 20]; \
        float4 h0_ = hp_[0], h1_ = hp_[1], h2_ = hp_[2], h3_ = hp_[3]; \
        float4 xv_ = *(const float4*)&s->xst[(k)][kq * 4]; \
        float p0 = dot4(A3, h3_, dot4(A2, h2_, dot4(A1, h1_, dot4(A0, h0_, dot4(xw0, xv_, 0.f))))); \
        float p1 = dot4(B3, h3_, dot4(B2, h2_, dot4(B1, h1_, dot4(B0, h0_, dot4(xw1, xv_, 0.f))))); \
        float p2 = dot4(C3, h3_, dot4(C2, h2_, dot4(C1, h1_, dot4(C0, h0_, dot4(xw2, xv_, 0.f))))); \
        float p3 = dot4(D3, h3_, dot4(D2, h2_, dot4(D1, h1_, dot4(D0, h0_, dot4(xw3, xv_, 0.f))))); \
        p0 += DPPF(p0, 0xB1); p1 += DPPF(p1, 0xB1); p2 += DPPF(p2, 0xB1); p3 += DPPF(p3, 0xB1); \
        p0 += DPPF(p0, 0x4E); p1 += DPPF(p1, 0x4E); p2 += DPPF(p2, 0x4E); p3 += DPPF(p3, 0x4E); \
        float gi = 1.0f - fast_rcp(__expf(p0 + bb0) + 1.0f); \
        float gf = 1.0f - fast_rcp(__expf(p1 + bb1) + 1.0f); \
        float gg = 1.0f - 2.0f * fast_rcp(__expf(2.0f * (p2 + bb2)) + 1.0f); \
        float go = 1.0f - fast_rcp(__expf(p3 + bb3) + 1.0f); \
        cst = fmaf(gf, cst, gi * gg); \
        float h_ = go * tanhfast(cst); \
        if (kq == 0) { s->hbuf[(k) & 1][(j >> 4) * 20 + (j & 15)] = h_; s->ring[(k)][j] = h_; } \
        __syncthreads(); \
    }

    for (int c = 0; c < 128; ++c) {
        if (tid == 0) {
            while (__hip_atomic_load(&cnt0[b * 128 + c], __ATOMIC_RELAXED, SCOPE_AGENT) < 16)
                __builtin_amdgcn_s_sleep(2);
        }
        __syncthreads();
        s->xst[tid >> 4][tid & 15] =
            __hip_atomic_load(fbase + c * 256 + tid, __ATOMIC_RELAXED, SCOPE_AGENT);
        __syncthreads();
        STEP0(0)  STEP0(1)  STEP0(2)  STEP0(3)
        STEP0(4)  STEP0(5)  STEP0(6)  STEP0(7)
        STEP0(8)  STEP0(9)  STEP0(10) STEP0(11)
        STEP0(12) STEP0(13) STEP0(14) STEP0(15)
        {
            ull* dst = (ull*)(hout + ((long)b * 2048 + c * 16) * 64);
            ull v0 = ((const ull*)s->ring)[tid];
            ull v1 = ((const ull*)s->ring)[tid + 256];
            __hip_atomic_store(dst + tid, v0, __ATOMIC_RELAXED, SCOPE_AGENT);
            __hip_atomic_store(dst + tid + 256, v1, __ATOMIC_RELAXED, SCOPE_AGENT);
            __syncthreads();
            if (tid == 0)
                __hip_atomic_store(&flag1[b * 128 + c], 1, __ATOMIC_RELAXED, SCOPE_AGENT);
        }
    }
#undef STEP0
}

// ================= layer-1 recurrence body (verbatim R8) =================
__device__ __forceinline__ void rec1_body(char* smemraw, int b,
    const float* __restrict__ h1o,
    const float* __restrict__ wih, const float* __restrict__ whh,
    const float* __restrict__ bih, const float* __restrict__ bhh,
    float* __restrict__ hout, int* __restrict__ flag1)
{
    RecS* s = (RecS*)smemraw;
    const int tid = threadIdx.x;
    const int j = tid >> 2, kq = tid & 3;

    const float4* pa = (const float4*)(whh + (0 * 64 + j) * 64 + kq * 16);
    const float4* pb = (const float4*)(whh + (1 * 64 + j) * 64 + kq * 16);
    const float4* pc_ = (const float4*)(whh + (2 * 64 + j) * 64 + kq * 16);
    const float4* pd = (const float4*)(whh + (3 * 64 + j) * 64 + kq * 16);
    float4 A0 = pa[0], A1 = pa[1], A2 = pa[2], A3 = pa[3];
    float4 B0 = pb[0], B1 = pb[1], B2 = pb[2], B3 = pb[3];
    float4 C0 = pc_[0], C1 = pc_[1], C2 = pc_[2], C3 = pc_[3];
    float4 D0 = pd[0], D1 = pd[1], D2 = pd[2], D3 = pd[3];
    const float4* qa = (const float4*)(wih + (0 * 64 + j) * 64 + kq * 16);
    const float4* qb = (const float4*)(wih + (1 * 64 + j) * 64 + kq * 16);
    const float4* qc = (const float4*)(wih + (2 * 64 + j) * 64 + kq * 16);
    const float4* qd = (const float4*)(wih + (3 * 64 + j) * 64 + kq * 16);
    float4 XA0 = qa[0], XA1 = qa[1], XA2 = qa[2], XA3 = qa[3];
    float4 XB0 = qb[0], XB1 = qb[1], XB2 = qb[2], XB3 = qb[3];
    float4 XC0 = qc[0], XC1 = qc[1], XC2 = qc[2], XC3 = qc[3];
    float4 XD0 = qd[0], XD1 = qd[1], XD2 = qd[2], XD3 = qd[3];
    const float bb0 = bih[j] + bhh[j];
    const float bb1 = bih[64 + j] + bhh[64 + j];
    const float bb2 = bih[128 + j] + bhh[128 + j];
    const float bb3 = bih[192 + j] + bhh[192 + j];

    if (tid < 64) s->hbuf[1][(tid >> 4) * 20 + (tid & 15)] = 0.0f;
    float cst = 0.0f;
    __syncthreads();

#define STEP1(k) { \
        const float4* hp_ = (const float4*)&s->hbuf[((k) + 1) & 1][kq * 20]; \
        float4 h0_ = hp_[0], h1_ = hp_[1], h2_ = hp_[2], h3_ = hp_[3]; \
        const float4* xp_ = (const float4*)&s->xst[(k)][kq * 20]; \
        float4 x0_ = xp_[0], x1_ = xp_[1], x2_ = xp_[2], x3_ = xp_[3]; \
        float p0 = dot4(A3, h3_, dot4(A2, h2_, dot4(A1, h1_, dot4(A0, h0_, \
                   dot4(XA3, x3_, dot4(XA2, x2_, dot4(XA1, x1_, dot4(XA0, x0_, 0.f)))))))); \
        float p1 = dot4(B3, h3_, dot4(B2, h2_, dot4(B1, h1_, dot4(B0, h0_, \
                   dot4(XB3, x3_, dot4(XB2, x2_, dot4(XB1, x1_, dot4(XB0, x0_, 0.f)))))))); \
        float p2 = dot4(C3, h3_, dot4(C2, h2_, dot4(C1, h1_, dot4(C0, h0_, \
                   dot4(XC3, x3_, dot4(XC2, x2_, dot4(XC1, x1_, dot4(XC0, x0_, 0.f)))))))); \
        float p3 = dot4(D3, h3_, dot4(D2, h2_, dot4(D1, h1_, dot4(D0, h0_, \
                   dot4(XD3, x3_, dot4(XD2, x2_, dot4(XD1, x1_, dot4(XD0, x0_, 0.f)))))))); \
        p0 += DPPF(p0, 0xB1); p1 += DPPF(p1, 0xB1); p2 += DPPF(p2, 0xB1); p3 += DPPF(p3, 0xB1); \
        p0 += DPPF(p0, 0x4E); p1 += DPPF(p1, 0x4E); p2 += DPPF(p2, 0x4E); p3 += DPPF(p3, 0x4E); \
        float gi = 1.0f - fast_rcp(__expf(p0 + bb0) + 1.0f); \
        float gf = 1.0f - fast_rcp(__expf(p1 + bb1) + 1.0f); \
        float gg = 1.0f - 2.0f * fast_rcp(__expf(2.0f * (p2 + bb2)) + 1.0f); \
        float go = 1.0f - fast_rcp(__expf(p3 + bb3) + 1.0f); \
        cst = fmaf(gf, cst, gi * gg); \
        float h_ = go * tanhfast(cst); \
        if (kq == 0) { s->hbuf[(k) & 1][(j >> 4) * 20 + (j & 15)] = h_; s->ring[(k)][j] = h_; } \
        __syncthreads(); \
    }

    for (int c = 0; c < 128; ++c) {
        if (tid == 0) {
            while (__hip_atomic_load(&flag1[b * 128 + c], __ATOMIC_RELAXED, SCOPE_AGENT) < 1)
                __builtin_amdgcn_s_sleep(2);
        }
        __syncthreads();
        {
            const ull* src = (const ull*)(h1o + ((long)b * 2048 + c * 16) * 64);
            ull v0 = __hip_atomic_load(src + tid, __ATOMIC_RELAXED, SCOPE_AGENT);
            ull v1 = __hip_atomic_load(src + tid + 256, __ATOMIC_RELAXED, SCOPE_AGENT);
            int u0 = tid, u1 = tid + 256;
            int k0 = u0 >> 5, p0i = (u0 & 31) * 2;
            int k1 = u1 >> 5, p1i = (u1 & 31) * 2;
            *(ull*)&s->xst[k0][(p0i >> 4) * 20 + (p0i & 15)] = v0;
            *(ull*)&s->xst[k1][(p1i >> 4) * 20 + (p1i & 15)] = v1;
        }
        __syncthreads();
        STEP1(0)  STEP1(1)  STEP1(2)  STEP1(3)
        STEP1(4)  STEP1(5)  STEP1(6)  STEP1(7)
        STEP1(8)  STEP1(9)  STEP1(10) STEP1(11)
        STEP1(12) STEP1(13) STEP1(14) STEP1(15)
        {
            float4* dst = (float4*)(hout + ((long)b * 2048 + c * 16) * 64);
            dst[tid] = ((const float4*)s->ring)[tid];
        }
    }
#undef STEP1
}

// ================= edge body: exact window-boundary terms + interior from a3f =================
__device__ __forceinline__ void edge_body(char* smemraw, int b, int t,
    const float* __restrict__ x,
    const float* __restrict__ w1,
    const float* __restrict__ b1, const float* __restrict__ g1,
    const float* __restrict__ be1, const float* __restrict__ m1, const float* __restrict__ vv1,
    const float* __restrict__ b2, const float* __restrict__ g2,
    const float* __restrict__ be2, const float* __restrict__ m2, const float* __restrict__ vv2,
    const float* __restrict__ b3, const float* __restrict__ g3,
    const float* __restrict__ be3, const float* __restrict__ m3, const float* __restrict__ vv3,
    const float* __restrict__ w2t2,
    const float4* __restrict__ w3p4, const float* __restrict__ w3p1,
    const float* __restrict__ a3f,
    float* __restrict__ feats, int* __restrict__ cnt0)
{
    EdgeS* s = (EdgeS*)smemraw;
    const int tid = threadIdx.x;

    // interior a3f staging (v3 = t .. t+31)
    if (tid < 128) {
        int dv = tid >> 2, o4 = (tid & 3) * 4;
        *(float4*)&s->pi[dv * 16 + o4] =
            *(const float4*)&a3f[((long)b * 2080 + t + dv) * 16 + o4];
    }
    // bn scale/offset
    if (tid < 64) {
        float sc = g1[tid] * rsqrtf(vv1[tid] + EPSV);
        s->s1[tid] = sc;
        s->t1[tid] = (b1[tid] - m1[tid]) * sc + be1[tid];
    } else if (tid < 96) {
        int o = tid - 64;
        float sc = g2[o] * rsqrtf(vv2[o] + EPSV);
        s->s2[o] = sc;
        s->t2[o] = (b2[o] - m2[o]) * sc + be2[o];
    } else if (tid < 112) {
        int o = tid - 96;
        float sc = g3[o] * rsqrtf(vv3[o] + EPSV);
        s->s3[o] = sc;
        s->t3[o] = (b3[o] - m3[o]) * sc + be3[o];
    } else if (tid < 136) {
        int j = tid - 112;   // xeL[j] = win[j-4] (window pad: 0 for j<4)
        float v = 0.0f;
        if (j >= 4 && j < 22) { int gi = t - 53 + j; if (gi >= 0) v = x[b * 2048 + gi]; }
        s->xeL[j] = v;
    } else if (tid < 160) {
        int j = tid - 136;   // xeR[j] = win[32+j] (0 for j>17)
        float v = 0.0f;
        if (j <= 17) { int gi = t - 17 + j; if (gi >= 0) v = x[b * 2048 + gi]; }
        s->xeR[j] = v;
    }
    // A1 guard zeros: per row slots {0,1,2,34,35,36}
    for (int idx = tid; idx < 384; idx += 256) {
        int o = idx / 6, z = idx - o * 6;
        s->A1[o * 40 + (z < 3 ? z : 31 + z)] = 0.0f;
    }
    // A2 guard zeros: per row slots {0,1,27,28}
    if (tid < 128) {
        int o = tid >> 2, z = tid & 3;
        s->A2[o * 32 + (z < 2 ? z : 25 + z)] = 0.0f;
    }
    __syncthreads();

    {   // conv1 edges: 64 o x 4 groups x 7 positions (28 = 14 left + 14 right)
        int o = tid >> 2, g = tid & 3;
        float wv[9];
        #pragma unroll
        for (int k = 0; k < 9; ++k) wv[k] = w1[o * 9 + k];
        float sc = s->s1[o], tc = s->t1[o];
        #pragma unroll
        for (int n = 0; n < 7; ++n) {
            int P = g * 7 + n;
            float acc = 0.0f;
            if (P < 14) {
                #pragma unroll
                for (int k = 0; k < 9; ++k) acc = fmaf(wv[k], s->xeL[P + k], acc);
                s->A1[o * 40 + 3 + P] = fmaxf(acc * sc + tc, 0.0f);
            } else {
                int pr = P - 14;
                #pragma unroll
                for (int k = 0; k < 9; ++k) acc = fmaf(wv[k], s->xeR[pr + k], acc);
                s->A1[o * 40 + 20 + pr] = fmaxf(acc * sc + tc, 0.0f);
            }
        }
    }
    __syncthreads();

    {   // conv2 edges: 32 o x 8 groups; group covers <=3 of {left e 0..10 | right e' 0..10}
        int o = tid >> 3, g = tid & 7;
        int side = g >> 2, gg = g & 3;
        int be_ = gg * 3;
        int cnt = (gg == 3) ? 2 : 3;
        int beta0 = side ? 20 + be_ : be_;
        float acc0 = 0.f, acc1 = 0.f, acc2 = 0.f;
        for (int i = 0; i < 64; ++i) {
            const float* rp = &s->A1[i * 40 + beta0];
            float av[9];
            #pragma unroll
            for (int c = 0; c < 9; ++c) av[c] = rp[c];
            const float4* wp = (const float4*)&w2t2[(i * 32 + o) * 8];
            float4 Wa = wp[0], Wb = wp[1];
            float wk[7] = {Wa.x, Wa.y, Wa.z, Wa.w, Wb.x, Wb.y, Wb.z};
            #pragma unroll
            for (int k = 0; k < 7; ++k) {
                acc0 = fmaf(wk[k], av[k], acc0);
                acc1 = fmaf(wk[k], av[k + 1], acc1);
                acc2 = fmaf(wk[k], av[k + 2], acc2);
            }
        }
        float sc = s->s2[o], tc = s->t2[o];
        float r0 = fmaxf(acc0 * sc + tc, 0.0f);
        float r1 = fmaxf(acc1 * sc + tc, 0.0f);
        float r2 = fmaxf(acc2 * sc + tc, 0.0f);
        int base = o * 32 + (side ? 16 + be_ : 2 + be_);
        s->A2[base] = r0;
        s->A2[base + 1] = r1;
        if (cnt == 3) s->A2[base + 2] = r2;
    }
    __syncthreads();

    {   // conv3 edges: 16 o x 16 groups; P3 = g, plus g<2 do P3 = 16+g  (18 = 9 left + 9 right)
        int o = tid & 15, g = tid >> 4;
        float sc = s->s3[o], tc = s->t3[o];
        #pragma unroll
        for (int rep = 0; rep < 2; ++rep) {
            int P3 = (rep == 0) ? g : 16 + g;
            if (rep == 1 && g >= 2) break;
            int tb = (P3 >= 9) ? 16 + (P3 - 9) : P3;
            float acc = 0.0f;
            for (int i = 0; i < 32; ++i) {
                const float* rp = &s->A2[i * 32 + tb];
                float4 wa = w3p4[i * 16 + o];
                float w4 = w3p1[i * 16 + o];
                acc = fmaf(wa.x, rp[0], acc);
                acc = fmaf(wa.y, rp[1], acc);
                acc = fmaf(wa.z, rp[2], acc);
                acc = fmaf(wa.w, rp[3], acc);
                acc = fmaf(w4,   rp[4], acc);
            }
            s->psumE[P3 * 16 + o] = fmaxf(acc * sc + tc, 0.0f);
        }
    }
    __syncthreads();

    if (tid < 16) {
        float e = 0.0f;
        #pragma unroll
        for (int P3 = 0; P3 < 18; ++P3) e += s->psumE[P3 * 16 + tid];
        float ii = 0.0f;
        #pragma unroll
        for (int dv = 0; dv < 32; ++dv) ii += s->pi[dv * 16 + tid];
        __hip_atomic_store(&feats[((long)b * 2048 + t) * 16 + tid], (e + ii) * (1.0f / 50.0f),
                           __ATOMIC_RELAXED, SCOPE_AGENT);
    }
    __syncthreads();   // drains vmcnt(0): feats stores complete before counter bump
    if (tid == 0)
        __hip_atomic_fetch_add(&cnt0[b * 128 + (t >> 4)], 1, __ATOMIC_RELAXED, SCOPE_AGENT);
}

// ================= fused: blocks 0-15 lstm0, 16-31 lstm1, 32+ edge (t-major) =================
__global__ __launch_bounds__(256, 2) void fused_kernel(
    const float* __restrict__ x,
    const float* __restrict__ w1, const float* __restrict__ b1,
    const float* __restrict__ g1, const float* __restrict__ be1,
    const float* __restrict__ m1, const float* __restrict__ vv1,
    const float* __restrict__ b2,
    const float* __restrict__ g2, const float* __restrict__ be2,
    const float* __restrict__ m2, const float* __restrict__ vv2,
    const float* __restrict__ b3,
    const float* __restrict__ g3, const float* __restrict__ be3,
    const float* __restrict__ m3, const float* __restrict__ vv3,
    const float* __restrict__ w2t2,
    const float4* __restrict__ w3p4, const float* __restrict__ w3p1,
    const float* __restrict__ a3f,
    const float* __restrict__ wih0, const float* __restrict__ whh0,
    const float* __restrict__ bih0, const float* __restrict__ bhh0,
    const float* __restrict__ wih1, const float* __restrict__ whh1,
    const float* __restrict__ bih1, const float* __restrict__ bhh1,
    float* __restrict__ feats, float* __restrict__ h1o, float* __restrict__ h2o,
    int* __restrict__ cnt0, int* __restrict__ flag1)
{
    __shared__ __align__(16) char smem[sizeof(EdgeS) > sizeof(RecS) ? sizeof(EdgeS) : sizeof(RecS)];

    if (blockIdx.x < 16) { rec0_body(smem, blockIdx.x, feats, wih0, whh0, bih0, bhh0, h1o, cnt0, flag1); return; }
    if (blockIdx.x < 32) { rec1_body(smem, blockIdx.x - 16, h1o, wih1, whh1, bih1, bhh1, h2o, flag1); return; }

    int w = blockIdx.x - 32;
    int b = w & 15;          // t-major: early t for all batches first
    int t = w >> 4;
    edge_body(smem, b, t, x, w1, b1, g1, be1, m1, vv1, b2, g2, be2, m2, vv2,
              b3, g3, be3, m3, vv3, w2t2, w3p4, w3p1, a3f, feats, cnt0);
}

// ---------------- FC head ----------------
__global__ __launch_bounds__(256) void fc_kernel(
    const float* __restrict__ h2o,
    const float* __restrict__ fc1w, const float* __restrict__ fc1b,
    const float* __restrict__ fc2w, const float* __restrict__ fc2b,
    float* __restrict__ out)
{
    int r = blockIdx.x * 256 + threadIdx.x;
    float h[64];
    const float4* hp = (const float4*)(h2o + (long)r * 64);
    #pragma unroll
    for (int i = 0; i < 16; ++i) {
        float4 v = hp[i];
        h[4 * i] = v.x; h[4 * i + 1] = v.y; h[4 * i + 2] = v.z; h[4 * i + 3] = v.w;
    }
    float l0 = fc2b[0], l1 = fc2b[1];
    #pragma unroll 4
    for (int j = 0; j < 32; ++j) {
        float z = fc1b[j];
        #pragma unroll
        for (int k = 0; k < 64; ++k) z = fmaf(h[k], fc1w[j * 64 + k], z);
        z = fmaxf(z, 0.0f);
        l0 = fmaf(z, fc2w[j], l0);
        l1 = fmaf(z, fc2w[32 + j], l1);
    }
    out[r * 2] = l0;
    out[r * 2 + 1] = l1;
}

extern "C" void kernel_launch(void* const* d_in, const int* in_sizes, int n_in,
                              void* d_out, int out_size, void* d_ws, size_t ws_size,
                              hipStream_t stream) {
    const float* x    = (const float*)d_in[0];
    const float* w1   = (const float*)d_in[1];
    const float* b1   = (const float*)d_in[2];
    const float* g1   = (const float*)d_in[3];
    const float* be1  = (const float*)d_in[4];
    const float* m1   = (const float*)d_in[5];
    const float* v1   = (const float*)d_in[6];
    const float* w2   = (const float*)d_in[7];
    const float* b2   = (const float*)d_in[8];
    const float* g2   = (const float*)d_in[9];
    const float* be2  = (const float*)d_in[10];
    const float* m2   = (const float*)d_in[11];
    const float* v2   = (const float*)d_in[12];
    const float* w3   = (const float*)d_in[13];
    const float* b3   = (const float*)d_in[14];
    const float* g3   = (const float*)d_in[15];
    const float* be3  = (const float*)d_in[16];
    const float* m3   = (const float*)d_in[17];
    const float* v3   = (const float*)d_in[18];
    const float* wih0 = (const float*)d_in[19];
    const float* whh0 = (const float*)d_in[20];
    const float* bih0 = (const float*)d_in[21];
    const float* bhh0 = (const float*)d_in[22];
    const float* wih1 = (const float*)d_in[23];
    const float* whh1 = (const float*)d_in[24];
    const float* bih1 = (const float*)d_in[25];
    const float* bhh1 = (const float*)d_in[26];
    const float* fc1w = (const float*)d_in[27];
    const float* fc1b = (const float*)d_in[28];
    const float* fc2w = (const float*)d_in[29];
    const float* fc2b = (const float*)d_in[30];
    float* out = (float*)d_out;

    float* ws    = (float*)d_ws;
    float* feats = ws;                            // 524288
    float* h2o   = feats + 32768 * 16;            // 2097152
    float* w2t2  = h2o + 32768 * 64;              // 16384
    float* w3p4f = w2t2 + 16384;                  // 2048
    float* w3p1  = w3p4f + 2048;                  // 512
    float* h1o   = w3p1 + 512;                    // 2097152
    float* a1f   = h1o + 32768 * 64;              // 16*2089*64 = 2139136
    float* a2f   = a1f + 16 * 2089 * 64;          // 16*2083*32 = 1066496
    float* a3f   = a2f + 16 * 2083 * 32;          // 16*2080*16 = 532480
    int*   cnt0  = (int*)(a3f + 16 * 2080 * 16);  // 2048
    int*   flag1 = cnt0 + 2048;                   // 2048

    hipLaunchKernelGGL(pack_kernel, dim3(82), dim3(256), 0, stream,
                       w2, w3, w2t2, (float4*)w3p4f, w3p1, cnt0);
    hipLaunchKernelGGL(conv1f_kernel, dim3(33, 16), dim3(256), 0, stream,
                       x, w1, b1, g1, be1, m1, v1, a1f);
    hipLaunchKernelGGL(conv2f_kernel, dim3(33, 16), dim3(256), 0, stream,
                       a1f, w2t2, b2, g2, be2, m2, v2, a2f);
    hipLaunchKernelGGL(conv3f_kernel, dim3(17, 16), dim3(256), 0, stream,
                       a2f, (const float4*)w3p4f, w3p1, b3, g3, be3, m3, v3, a3f);
    hipLaunchKernelGGL(fused_kernel, dim3(32 + 32768), dim3(256), 0, stream,
                       x, w1, b1, g1, be1, m1, v1, b2, g2, be2, m2, v2,
                       b3, g3, be3, m3, v3, w2t2, (const float4*)w3p4f, w3p1, a3f,
                       wih0, whh0, bih0, bhh0, wih1, whh1, bih1, bhh1,
                       feats, h1o, h2o, cnt0, flag1);
    hipLaunchKernelGGL(fc_kernel, dim3(128), dim3(256), 0, stream,
                       h2o, fc1w, fc1b, fc2w, fc2b, out);
}